// Round 19
// baseline (252.873 us; speedup 1.0000x reference)
//
#include <hip/hip_runtime.h>

typedef unsigned short u16;
typedef unsigned int   u32;
typedef unsigned long long u64;
typedef short s16x8 __attribute__((ext_vector_type(8)));   // 8 x bf16 bits (4 VGPRs)
typedef float f32x4 __attribute__((ext_vector_type(4)));   // MFMA accumulator

#define NPTS   16384
#define KNNK   20
#define SLOTS3 12      // s0 stack slots (trigger 4, growth <= 8 => max 11)
#define TRIG3  4
#define NSEG   16      // s1x candidate parts per query
#define PSZ    1024    // candidates per part
#define SCAP   24      // survivor cap per (query, part)  [E~5; P(overflow) ~1e-4 total]

#define MFMA_BF16 __builtin_amdgcn_mfma_f32_16x16x32_bf16

__device__ __forceinline__ u16 f2bf(float x) {
  u32 u = __builtin_bit_cast(u32, x);
  u32 r = (u + 0x7FFFu + ((u >> 16) & 1u)) >> 16;   // RNE
  return (u16)r;
}
__device__ __forceinline__ float bf2f(u16 b) {
  u32 u = ((u32)b) << 16;
  return __builtin_bit_cast(float, u);
}
__device__ __forceinline__ float dist2(float4 qp, float4 cd) {
  float dot = fmaf(qp.x, cd.x, fmaf(qp.y, cd.y, qp.z * cd.z));
  return fmaf(-2.0f, dot, qp.w + cd.w);
}

// ---------------------------------------------------------------- prep: pos4 = (x,y,z,|p|^2)
__global__ __launch_bounds__(256) void knnconv_prep(const float* __restrict__ pos,
                                                    float4* __restrict__ pos4) {
  int i = blockIdx.x * 256 + threadIdx.x;
  float x = pos[i * 3 + 0], y = pos[i * 3 + 1], z = pos[i * 3 + 2];
  float sq = (x * x + y * y) + z * z;    // f32 screen only; f64 re-rank decides final set
  pos4[i] = make_float4(x, y, z, sq);
}

// ---------------------------------------------------------------- s0: sample threshold
// grid 256 (query-group); block 1024 = 16 waves. lane = query; wave wv scans 256
// samples (every 4th point). Each wave keeps only TOP-3 (lazy stack, 3-stage
// pair-carry ladder). tau = 20th smallest of the 48-value union: provable
// superset bound (>=20 full points within tau).
__global__ __launch_bounds__(1024) void knnconv_s0(const float4* __restrict__ pos4,
                                                   float* __restrict__ tau) {
  __shared__ float sd[SLOTS3 * 1024];    // 48KB per-lane stacks
  __shared__ float md[16][64][4];        // 16KB sorted top-3 + INF sentinel
  const int tid  = threadIdx.x;
  const int lane = tid & 63;
  const int wv   = __builtin_amdgcn_readfirstlane(tid >> 6);   // 0..15, uniform
  const int qg   = blockIdx.x;
  const int q    = qg * 64 + lane;
  const float4 qp = pos4[q];
  const float INF = __builtin_inff();

  float t0v = INF, t1v = INF, t2v = INF; // sorted top-3 in registers
  float thrF = INF;
  int cnt = 0;
  const int kbase = wv * 256;            // sample index base (sample i -> point 4i)

#define FLUSH3()                                                      \
  { _Pragma("unroll 1")                                               \
    for (int e = 0; e < SLOTS3; e += 2) {                             \
      if (!__any(e < cnt)) break;                                     \
      float lo = (e     < cnt) ? sd[e * 1024 + tid]       : INF;      \
      float hi = (e + 1 < cnt) ? sd[(e + 1) * 1024 + tid] : INF;      \
      float a_ = fminf(lo, hi), b_ = fmaxf(lo, hi);                   \
      lo = a_; hi = b_;                                               \
      { float m = fminf(lo, t0v), x = fmaxf(lo, t0v);                 \
        t0v = m; lo = fminf(x, hi); hi = fmaxf(x, hi); }              \
      { float m = fminf(lo, t1v), x = fmaxf(lo, t1v);                 \
        t1v = m; lo = fminf(x, hi); hi = fmaxf(x, hi); }              \
      t2v = fminf(lo, t2v);                                           \
    }                                                                 \
    thrF = t2v;                                                       \
    cnt = 0; }

  for (int t0 = 0; t0 < 256; t0 += 8) {
    float4 g[8];
    #pragma unroll
    for (int u = 0; u < 8; ++u) g[u] = pos4[(kbase + t0 + u) * 4];  // wave-uniform loads
    #pragma unroll
    for (int u = 0; u < 8; ++u) {
      float d2 = dist2(qp, g[u]);
      sd[cnt * 1024 + tid] = d2;                       // unconditional (slot <= 10 valid)
      cnt += (d2 < thrF) ? 1 : 0;                      // branchless accept
    }
    if (__any(cnt >= TRIG3)) { FLUSH3(); }
  }
  FLUSH3();

  md[wv][lane][0] = t0v;
  md[wv][lane][1] = t1v;
  md[wv][lane][2] = t2v;
  md[wv][lane][3] = INF;                 // sentinel: heads may clamp at 3
  __syncthreads();

  if (tid < 64) {                        // 16-way merge of top-3 lists, take 20th
    int ql = tid;
    int h0=0,h1=0,h2=0,h3=0,h4=0,h5=0,h6=0,h7=0;
    int h8=0,h9=0,h10=0,h11=0,h12=0,h13=0,h14=0,h15=0;
    float last = INF;
    for (int r = 0; r < KNNK; ++r) {     // 48 finite values exist -> last finite
      float c0 = md[ 0][ql][h0],  c1 = md[ 1][ql][h1];
      float c2 = md[ 2][ql][h2],  c3 = md[ 3][ql][h3];
      float c4 = md[ 4][ql][h4],  c5 = md[ 5][ql][h5];
      float c6 = md[ 6][ql][h6],  c7 = md[ 7][ql][h7];
      float c8 = md[ 8][ql][h8],  c9 = md[ 9][ql][h9];
      float cA = md[10][ql][h10], cB = md[11][ql][h11];
      float cC = md[12][ql][h12], cD = md[13][ql][h13];
      float cE = md[14][ql][h14], cF = md[15][ql][h15];
      float bv = c0; int bw = 0;
      if (c1 < bv) { bv = c1; bw = 1; }
      if (c2 < bv) { bv = c2; bw = 2; }
      if (c3 < bv) { bv = c3; bw = 3; }
      if (c4 < bv) { bv = c4; bw = 4; }
      if (c5 < bv) { bv = c5; bw = 5; }
      if (c6 < bv) { bv = c6; bw = 6; }
      if (c7 < bv) { bv = c7; bw = 7; }
      if (c8 < bv) { bv = c8; bw = 8; }
      if (c9 < bv) { bv = c9; bw = 9; }
      if (cA < bv) { bv = cA; bw = 10; }
      if (cB < bv) { bv = cB; bw = 11; }
      if (cC < bv) { bv = cC; bw = 12; }
      if (cD < bv) { bv = cD; bw = 13; }
      if (cE < bv) { bv = cE; bw = 14; }
      if (cF < bv) { bv = cF; bw = 15; }
      last = bv;
      h0  += (bw==0);  h1  += (bw==1);  h2  += (bw==2);  h3  += (bw==3);
      h4  += (bw==4);  h5  += (bw==5);  h6  += (bw==6);  h7  += (bw==7);
      h8  += (bw==8);  h9  += (bw==9);  h10 += (bw==10); h11 += (bw==11);
      h12 += (bw==12); h13 += (bw==13); h14 += (bw==14); h15 += (bw==15);
    }
    tau[qg * 64 + ql] = last * 1.00001f;
  }
}

// ---------------------------------------------------------------- s1x: transposed screen + ballot compaction
// grid 1024 = 256 qg x 4 part-blocks; block 4 waves; wave -> part = pb*4+wv.
// LANE = CANDIDATE: 64 candidates/window via per-lane coalesced global_load
// (in-order, depth-2 prefetch hidden under 64 query-iters of compute). Queries
// broadcast from 1KB LDS. Accept mask = vcc (free ballot); rare path
// (wave-uniform, ~27% of iters) does shfl-base + popcount-prefix scatter into
// the private per-(q,part) segment; cnt lives in lane j for query j.
// Survivor order = (window, lane) = ascending candidate idx -> deterministic,
// identical set to prior rounds (accept arithmetic bit-identical).
__global__ __launch_bounds__(256) void knnconv_s1x(const float4* __restrict__ pos4,
                                                   const float* __restrict__ tau,
                                                   u16* __restrict__ g1,
                                                   u16* __restrict__ gcnt) {
  __shared__ float4 sQ[64];              // (qx,qy,qz, Qt)
  const int tid  = threadIdx.x;
  const int lane = tid & 63;
  const int wv   = tid >> 6;
  const int qg   = blockIdx.x >> 2;
  const int pb   = blockIdx.x & 3;
  const int part = pb * 4 + wv;          // 0..15, one wave owns one part
  const int qbase = qg * 64;
  if (tid < 64) {
    float4 P = pos4[qbase + tid];
    sQ[tid] = make_float4(P.x, P.y, P.z, 0.5f * (tau[qbase + tid] - P.w));
  }
  __syncthreads();

  const int cbase = part * PSZ;
  int cnt = 0;                           // lane j holds survivor count of query qbase+j

#define S1WIN(CD, W)                                                  \
  { const float cx_ = CD.x, cy_ = CD.y, cz_ = CD.z;                   \
    const float cw2_ = 0.5f * CD.w;                                   \
    _Pragma("unroll 16")                                              \
    for (int j = 0; j < 64; ++j) {                                    \
      float4 Q = sQ[j];                                               \
      float dot = fmaf(Q.x, cx_, fmaf(Q.y, cy_, Q.z * cz_));          \
      bool acc = (cw2_ - dot) <= Q.w;                                 \
      u64 mask = __ballot(acc);                                       \
      if (mask) {                       /* wave-uniform branch */     \
        int base = __shfl(cnt, j);                                    \
        int pc = __popcll(mask);                                      \
        if (acc) {                                                    \
          int slot = base + __popcll(mask & ((1ULL << lane) - 1));    \
          if (slot < SCAP)                                            \
            g1[((qbase + j) * NSEG + part) * SCAP + slot] =           \
                (u16)(cbase + (W) * 64 + lane);                       \
        }                                                             \
        cnt += (lane == j) ? pc : 0;                                  \
      }                                                               \
    } }

  float4 A = pos4[cbase + 0 * 64 + lane];
  float4 B = pos4[cbase + 1 * 64 + lane];
  #pragma unroll 1
  for (int w = 0; w < 16; w += 2) {
    float4 nA = pos4[cbase + min(w + 2, 15) * 64 + lane];  // prefetch (dup of 15 on tail, discarded)
    S1WIN(A, w);
    float4 nB = pos4[cbase + min(w + 3, 15) * 64 + lane];
    S1WIN(B, w + 1);
    A = nA; B = nB;
  }
  gcnt[(qbase + lane) * NSEG + part] = (u16)min(cnt, SCAP);
}

// ---------------------------------------------------------------- s2: gather + f64 re-rank
// block = 16 queries x 16 segment-threads; keys[16][256] u64; rank-count.
__global__ __launch_bounds__(256) void knnconv_s2(const float4* __restrict__ pos4,
                                                  const u16* __restrict__ g1,
                                                  const u16* __restrict__ gcnt,
                                                  u16* __restrict__ knn_out) {
  __shared__ u64 keys[16 * 256];         // 32KB
  __shared__ int Tq[16];
  const int tid = threadIdx.x;
  const int iq = tid >> 4, s = tid & 15;
  const int q0 = blockIdx.x * 16;
  const int q = q0 + iq;

  #pragma unroll
  for (int i = 0; i < 16; ++i) keys[i * 256 + tid] = ~0ULL;
  __syncthreads();

  int off = 0, T = 0;
  #pragma unroll
  for (int j = 0; j < NSEG; ++j) {
    int cj = gcnt[q * NSEG + j];
    off += (j < s) ? cj : 0;
    T += cj;
  }
  if (s == 15) Tq[iq] = min(T, 256);
  int myc = gcnt[q * NSEG + s];
  float4 P = pos4[q];
  for (int i = 0; i < myc; ++i) {
    int pos = off + i;
    if (pos >= 256) break;               // deterministic clamp (P ~ 0)
    int cidx = (int)g1[(q * NSEG + s) * SCAP + i];
    float4 C = pos4[cidx];
    double qx = P.x, qy = P.y, qz = P.z;
    double cx = C.x, cy = C.y, cz = C.z;
    double sqq = qx * qx + qy * qy + qz * qz;
    double sqc = cx * cx + cy * cy + cz * cz;
    double dot = qx * cx + qy * cy + qz * cz;
    double d   = (sqq + sqc) - 2.0 * dot;              // exact to ~1e-16
    float df = fmaxf((float)d, 0.0f);                  // one rounding, 6e-8 rel
    keys[iq * 256 + pos] = ((u64)__builtin_bit_cast(u32, df) << 14) | (u32)cidx;
  }
  __syncthreads();

  #pragma unroll 1
  for (int t = 0; t < 16; ++t) {         // uniform per-block iteration
    int T2 = Tq[t];
    if (tid < T2) {
      u64 kj = keys[t * 256 + tid];
      const u64* row = keys + t * 256;
      int r = 0;
      for (int k = 0; k < T2; ++k) r += (row[k] < kj) ? 1 : 0;   // broadcast reads
      if (r < KNNK)
        knn_out[(q0 + t) * KNNK + r] = (u16)(kj & 0x3FFFu);
    }
  }
}

// ---------------------------------------------------------------- W1/W2 -> pre-swizzled bf16 (one-shot)
__global__ __launch_bounds__(256) void knnconv_wprep(const float* __restrict__ W1,
                                                     const float* __restrict__ W2,
                                                     u16* __restrict__ w1bf,
                                                     u16* __restrict__ w2bf) {
  int b = blockIdx.x;
  if (b < 128) {
    int e = b * 256 + threadIdx.x;       // 32768 entries
    int n = e >> 7, kk = e & 127;
    float v;
    if (n < 128) v = W1[(128 + kk) * 128 + n];                              // W1d
    else { int n2 = n - 128; v = W1[kk * 128 + n2] - W1[(128 + kk) * 128 + n2]; }  // W1c-W1d
    w1bf[(n * 256 + ((kk * 2) ^ ((n & 7) << 4))) >> 1] = f2bf(v);
  } else {
    int e = (b - 128) * 256 + threadIdx.x;   // 16384 entries
    int n = e >> 7, kk = e & 127;
    w2bf[(n * 256 + ((kk * 2) ^ ((n & 7) << 4))) >> 1] = f2bf(W2[kk * 128 + n]);
  }
}

// ---------------------------------------------------------------- precompute a = f@W1d (bf16), c = f@(W1c-W1d)+b1 (f32)
__global__ __launch_bounds__(256) void knnconv_prec(const float* __restrict__ feat,
                                                    const u16* __restrict__ w1bf,
                                                    const float* __restrict__ b1,
                                                    u16* __restrict__ a_out,
                                                    float* __restrict__ c_out) {
  __shared__ char sW[65536];   // WT[n=256][k=128] bf16, pre-swizzled (linear copy)
  __shared__ char sF[16384];   // FA[m=64][k=128] bf16, XOR-swizzled
  const int tid = threadIdx.x;
  { // linear coalesced copy of pre-swizzled W1-combined
    const uint4* src = (const uint4*)w1bf;
    uint4* dst = (uint4*)sW;
    #pragma unroll
    for (int r = 0; r < 16; ++r) dst[r * 256 + tid] = src[r * 256 + tid];
  }
  { // stage FA rows (bf16x8 per lane)
    int sub = tid & 15, r0 = tid >> 4;
    int m0 = blockIdx.x * 64;
    for (int rr = 0; rr < 4; ++rr) {
      int r = r0 + rr * 16;
      const float* src = feat + (m0 + r) * 128 + sub * 8;
      float4 v0 = *(const float4*)src;
      float4 v1 = *(const float4*)(src + 4);
      u32 p0 = (u32)f2bf(v0.x) | ((u32)f2bf(v0.y) << 16);
      u32 p1 = (u32)f2bf(v0.z) | ((u32)f2bf(v0.w) << 16);
      u32 p2 = (u32)f2bf(v1.x) | ((u32)f2bf(v1.y) << 16);
      u32 p3 = (u32)f2bf(v1.z) | ((u32)f2bf(v1.w) << 16);
      *(uint4*)(sF + r * 256 + ((sub * 16) ^ ((r & 7) << 4))) = make_uint4(p0, p1, p2, p3);
    }
  }
  __syncthreads();
  const int lane = tid & 63, wv = tid >> 6;
  const int l15 = lane & 15, l4 = lane >> 4;
  f32x4 acc[4][4];
  #pragma unroll
  for (int a = 0; a < 4; ++a)
    #pragma unroll
    for (int b = 0; b < 4; ++b) acc[a][b] = (f32x4){0.f, 0.f, 0.f, 0.f};
  #pragma unroll
  for (int kk = 0; kk < 4; ++kk) {
    int kb = kk * 64 + l4 * 16;
    s16x8 af[4], bfr[4];
    #pragma unroll
    for (int mt = 0; mt < 4; ++mt) {
      int row = mt * 16 + l15;
      af[mt] = *(const s16x8*)(sF + row * 256 + (kb ^ ((row & 7) << 4)));
    }
    #pragma unroll
    for (int nt = 0; nt < 4; ++nt) {
      int n = (wv * 4 + nt) * 16 + l15;
      bfr[nt] = *(const s16x8*)(sW + n * 256 + (kb ^ ((n & 7) << 4)));
    }
    #pragma unroll
    for (int mt = 0; mt < 4; ++mt)
      #pragma unroll
      for (int nt = 0; nt < 4; ++nt)
        acc[mt][nt] = MFMA_BF16(af[mt], bfr[nt], acc[mt][nt], 0, 0, 0);
  }
  int m0 = blockIdx.x * 64;
  #pragma unroll
  for (int nt = 0; nt < 4; ++nt) {
    int n = (wv * 4 + nt) * 16 + l15;
    float bias = (n >= 128) ? b1[n - 128] : 0.0f;
    #pragma unroll
    for (int mt = 0; mt < 4; ++mt)
      #pragma unroll
      for (int r = 0; r < 4; ++r) {
        int m = m0 + mt * 16 + l4 * 4 + r;    // C/D: row=(l>>4)*4+reg, col=l&15
        float v = acc[mt][nt][r];
        if (n < 128) a_out[m * 128 + n] = f2bf(v);
        else         c_out[m * 128 + (n - 128)] = v + bias;
      }
  }
}

// ---------------------------------------------------------------- fused gather + relu + GEMM2 + max
__global__ __launch_bounds__(256) void knnconv_conv(const u16* __restrict__ knn,
                                                    const u16* __restrict__ a_in,
                                                    const float* __restrict__ c_in,
                                                    const u16* __restrict__ w2bf,
                                                    const float* __restrict__ b2,
                                                    float* __restrict__ out) {
  __shared__ char lds[77824];     // [0,40960): A / H2  | [40960,73728): W2T | [73728,77824): c rows
  char* sA = lds;
  char* sW = lds + 40960;
  char* sC = lds + 73728;
  const int tid = threadIdx.x;
  const int q0 = blockIdx.x * 8;

  { // stage c rows for the 8 queries
    int row = tid >> 5, ch4 = (tid & 31) * 4;
    *(float4*)(sC + (row * 128 + ch4) * 4) = *(const float4*)(c_in + (q0 + row) * 128 + ch4);
  }
  __syncthreads();
  { // copy pre-swizzled W2 bf16 (linear copy; layout already swizzled)
    const uint4* src = (const uint4*)w2bf;
    uint4* dst = (uint4*)sW;
    #pragma unroll
    for (int r = 0; r < 8; ++r) dst[r * 256 + tid] = src[r * 256 + tid];
  }
  { // stage A: row r = (query il, neighbor ke): relu(a[idx] + c[il]) -> bf16, swizzled
    int sub = tid & 15, rr = tid >> 4;
    for (int p = 0; p < 10; ++p) {
      int r = p * 16 + rr;
      int il = r / 20;
      int ke = r - il * 20;
      int idx = (int)knn[(q0 + il) * KNNK + ke];
      uint4 av = *(const uint4*)(a_in + idx * 128 + sub * 8);
      float4 c0 = *(const float4*)(sC + (il * 128 + sub * 8) * 4);
      float4 c1 = *(const float4*)(sC + (il * 128 + sub * 8 + 4) * 4);
      float h0 = fmaxf(bf2f((u16)(av.x & 0xFFFF)) + c0.x, 0.f);
      float h1 = fmaxf(bf2f((u16)(av.x >> 16))    + c0.y, 0.f);
      float h2 = fmaxf(bf2f((u16)(av.y & 0xFFFF)) + c0.z, 0.f);
      float h3 = fmaxf(bf2f((u16)(av.y >> 16))    + c0.w, 0.f);
      float h4 = fmaxf(bf2f((u16)(av.z & 0xFFFF)) + c1.x, 0.f);
      float h5 = fmaxf(bf2f((u16)(av.z >> 16))    + c1.y, 0.f);
      float h6 = fmaxf(bf2f((u16)(av.w & 0xFFFF)) + c1.z, 0.f);
      float h7 = fmaxf(bf2f((u16)(av.w >> 16))    + c1.w, 0.f);
      u32 p0 = (u32)f2bf(h0) | ((u32)f2bf(h1) << 16);
      u32 p1 = (u32)f2bf(h2) | ((u32)f2bf(h3) << 16);
      u32 p2 = (u32)f2bf(h4) | ((u32)f2bf(h5) << 16);
      u32 p3 = (u32)f2bf(h6) | ((u32)f2bf(h7) << 16);
      *(uint4*)(sA + r * 256 + ((sub * 16) ^ ((r & 7) << 4))) = make_uint4(p0, p1, p2, p3);
    }
  }
  __syncthreads();
  const int lane = tid & 63, wv = tid >> 6;
  const int l15 = lane & 15, l4 = lane >> 4;
  f32x4 acc[10][2];
  #pragma unroll
  for (int mt = 0; mt < 10; ++mt) { acc[mt][0] = (f32x4){0,0,0,0}; acc[mt][1] = (f32x4){0,0,0,0}; }
  #pragma unroll
  for (int kk = 0; kk < 4; ++kk) {
    int kb = kk * 64 + l4 * 16;
    s16x8 b0, b1r;
    { int n = (wv * 2 + 0) * 16 + l15; b0  = *(const s16x8*)(sW + n * 256 + (kb ^ ((n & 7) << 4))); }
    { int n = (wv * 2 + 1) * 16 + l15; b1r = *(const s16x8*)(sW + n * 256 + (kb ^ ((n & 7) << 4))); }
    #pragma unroll
    for (int mt = 0; mt < 10; ++mt) {
      int row = mt * 16 + l15;
      s16x8 a = *(const s16x8*)(sA + row * 256 + (kb ^ ((row & 7) << 4)));
      acc[mt][0] = MFMA_BF16(a, b0,  acc[mt][0], 0, 0, 0);
      acc[mt][1] = MFMA_BF16(a, b1r, acc[mt][1], 0, 0, 0);
    }
  }
  __syncthreads();              // all waves done reading A before H2 overwrite
  #pragma unroll
  for (int mt = 0; mt < 10; ++mt)
    #pragma unroll
    for (int nt = 0; nt < 2; ++nt) {
      int n = (wv * 2 + nt) * 16 + l15;
      #pragma unroll
      for (int r = 0; r < 4; ++r) {
        int row = mt * 16 + l4 * 4 + r;
        *(u16*)(sA + row * 256 + n * 2) = f2bf(acc[mt][nt][r]);  // H2, plain layout
      }
    }
  __syncthreads();
  { // max over 20 neighbors + b2
    int ch = tid & 127, g = tid >> 7;
    float bias = b2[ch];
    for (int pp = 0; pp < 4; ++pp) {
      int qq = pp * 2 + g;
      float mx = -__builtin_inff();
      #pragma unroll
      for (int e = 0; e < KNNK; ++e)
        mx = fmaxf(mx, bf2f(*(const u16*)(sA + (qq * 20 + e) * 256 + ch * 2)));
      out[(q0 + qq) * 128 + ch] = mx + bias;
    }
  }
}

// ---------------------------------------------------------------- launch
extern "C" void kernel_launch(void* const* d_in, const int* in_sizes, int n_in,
                              void* d_out, int out_size, void* d_ws, size_t ws_size,
                              hipStream_t stream) {
  const float* pos  = (const float*)d_in[0];
  const float* feat = (const float*)d_in[1];
  const float* W1   = (const float*)d_in[2];
  const float* b1   = (const float*)d_in[3];
  const float* W2   = (const float*)d_in[4];
  const float* b2   = (const float*)d_in[5];
  float* out = (float*)d_out;
  char* ws = (char*)d_ws;
  // ws layout (aliases noted):
  //  [0,256K)              pos4 (prep..s2)        -> w1bf 64KB + w2bf 32KB (wprep..conv)
  //  [256K,917504)         knn u16 (s2..conv)
  //  [917504,13500416)     g1 [16384][16][24] u16 (s1x..s2) -> a_buf 4MB + c_buf 8MB (prec..conv)
  //  [13500416,14024704)   gcnt [16384][16] u16 (s1x..s2)
  //  [14024704,14090240)   tau [16384] f32 (s0..s1x)
  float4* pos4  = (float4*)ws;
  u16*    w1bf  = (u16*)ws;
  u16*    w2bf  = (u16*)(ws + 65536);
  u16*    knn   = (u16*)(ws + 262144);
  u16*    g1    = (u16*)(ws + 917504);
  u16*    a_buf = (u16*)(ws + 917504);
  float*  c_buf = (float*)(ws + 5111808);
  u16*    gcnt  = (u16*)(ws + 13500416);
  float*  tau   = (float*)(ws + 14024704);
  if (ws_size < 14090240) return;   // insufficient scratch (would corrupt)

  knnconv_prep<<<64, 256, 0, stream>>>(pos, pos4);
  knnconv_s0<<<256, 1024, 0, stream>>>(pos4, tau);
  knnconv_s1x<<<1024, 256, 0, stream>>>(pos4, tau, g1, gcnt);
  knnconv_s2<<<1024, 256, 0, stream>>>(pos4, g1, gcnt, knn);
  knnconv_wprep<<<192, 256, 0, stream>>>(W1, W2, w1bf, w2bf);          // overwrites pos4 (dead)
  knnconv_prec<<<256, 256, 0, stream>>>(feat, w1bf, b1, a_buf, c_buf); // overwrites g1 (dead)
  knnconv_conv<<<2048, 256, 0, stream>>>(knn, a_buf, c_buf, w2bf, b2, out);
}

// Round 20
// 219.984 us; speedup vs baseline: 1.1495x; 1.1495x over previous
//
#include <hip/hip_runtime.h>

typedef unsigned short u16;
typedef unsigned int   u32;
typedef unsigned long long u64;
typedef short s16x8 __attribute__((ext_vector_type(8)));   // 8 x bf16 bits (4 VGPRs)
typedef float f32x4 __attribute__((ext_vector_type(4)));   // MFMA accumulator

#define NPTS   16384
#define KNNK   20
#define SLOTS3 12      // s0 stack slots (trigger 4, growth <= 8 => max 11)
#define TRIG3  4
#define NSEG   16      // s1x candidate parts per query
#define PSZ    1024    // candidates per part
#define SCAP   24      // survivor cap per (query, part)  [E~5; P(overflow) ~1e-4 total]

#define MFMA_BF16 __builtin_amdgcn_mfma_f32_16x16x32_bf16

__device__ __forceinline__ u16 f2bf(float x) {
  u32 u = __builtin_bit_cast(u32, x);
  u32 r = (u + 0x7FFFu + ((u >> 16) & 1u)) >> 16;   // RNE
  return (u16)r;
}
__device__ __forceinline__ float bf2f(u16 b) {
  u32 u = ((u32)b) << 16;
  return __builtin_bit_cast(float, u);
}
__device__ __forceinline__ float dist2(float4 qp, float4 cd) {
  float dot = fmaf(qp.x, cd.x, fmaf(qp.y, cd.y, qp.z * cd.z));
  return fmaf(-2.0f, dot, qp.w + cd.w);
}

// ---------------------------------------------------------------- prep: pos4 = (x,y,z,|p|^2)
__global__ __launch_bounds__(256) void knnconv_prep(const float* __restrict__ pos,
                                                    float4* __restrict__ pos4) {
  int i = blockIdx.x * 256 + threadIdx.x;
  float x = pos[i * 3 + 0], y = pos[i * 3 + 1], z = pos[i * 3 + 2];
  float sq = (x * x + y * y) + z * z;    // f32 screen only; f64 re-rank decides final set
  pos4[i] = make_float4(x, y, z, sq);
}

// ---------------------------------------------------------------- s0: sample threshold
// grid 256; block 1024 = 16 waves; lane = query. Wave wv scans 256 samples
// (every 4th point) in 4 windows of 64: lane l loads sample w*64+l (coalesced,
// depth-2 prefetch), stages to wave-private LDS, processing reads slot s
// uniformly (broadcast, conflict-free, NO barriers -- intra-wave lgkmcnt).
// Sample order identical to prior rounds -> bit-identical tau. Top-3 lazy
// stack + 16-way merge -> tau = 20th of 48-value union (provable superset).
__global__ __launch_bounds__(1024) void knnconv_s0(const float4* __restrict__ pos4,
                                                   float* __restrict__ tau) {
  __shared__ float sd[SLOTS3 * 1024];    // 48KB per-lane stacks
  __shared__ float md[16][64][4];        // 16KB sorted top-3 + INF sentinel
  __shared__ float4 stg[16][2][64];      // 32KB wave-private staging
  const int tid  = threadIdx.x;
  const int lane = tid & 63;
  const int wv   = tid >> 6;             // 0..15
  const int qg   = blockIdx.x;
  const int q    = qg * 64 + lane;
  const float4 qp = pos4[q];
  const float INF = __builtin_inff();

  float t0v = INF, t1v = INF, t2v = INF; // sorted top-3 in registers
  float thrF = INF;
  int cnt = 0;
  const int kbase = wv * 256;            // sample index base (sample i -> point 4i)

#define FLUSH3()                                                      \
  { _Pragma("unroll 1")                                               \
    for (int e = 0; e < SLOTS3; e += 2) {                             \
      if (!__any(e < cnt)) break;                                     \
      float lo = (e     < cnt) ? sd[e * 1024 + tid]       : INF;      \
      float hi = (e + 1 < cnt) ? sd[(e + 1) * 1024 + tid] : INF;      \
      float a_ = fminf(lo, hi), b_ = fmaxf(lo, hi);                   \
      lo = a_; hi = b_;                                               \
      { float m = fminf(lo, t0v), x = fmaxf(lo, t0v);                 \
        t0v = m; lo = fminf(x, hi); hi = fmaxf(x, hi); }              \
      { float m = fminf(lo, t1v), x = fmaxf(lo, t1v);                 \
        t1v = m; lo = fminf(x, hi); hi = fmaxf(x, hi); }              \
      t2v = fminf(lo, t2v);                                           \
    }                                                                 \
    thrF = t2v;                                                       \
    cnt = 0; }

  float4 r = pos4[(kbase + 0 * 64 + lane) * 4];
  stg[wv][0][lane] = r;
  r = pos4[(kbase + 1 * 64 + lane) * 4];           // prefetch window 1
  #pragma unroll 1
  for (int w = 0; w < 4; ++w) {
    const float4* wb = stg[wv][w & 1];
    #pragma unroll 1
    for (int g8 = 0; g8 < 64; g8 += 8) {
      #pragma unroll
      for (int u = 0; u < 8; ++u) {
        float d2 = dist2(qp, wb[g8 + u]);          // uniform ds_read broadcast
        sd[cnt * 1024 + tid] = d2;                 // unconditional (slot <= 10)
        cnt += (d2 < thrF) ? 1 : 0;
      }
      if (__any(cnt >= TRIG3)) { FLUSH3(); }
    }
    if (w < 3) {
      stg[wv][(w + 1) & 1][lane] = r;              // vmcnt long satisfied
      if (w < 2) r = pos4[(kbase + (w + 2) * 64 + lane) * 4];
    }
  }
  FLUSH3();

  md[wv][lane][0] = t0v;
  md[wv][lane][1] = t1v;
  md[wv][lane][2] = t2v;
  md[wv][lane][3] = INF;                 // sentinel: heads may clamp at 3
  __syncthreads();

  if (tid < 64) {                        // 16-way merge of top-3 lists, take 20th
    int ql = tid;
    int h0=0,h1=0,h2=0,h3=0,h4=0,h5=0,h6=0,h7=0;
    int h8=0,h9=0,h10=0,h11=0,h12=0,h13=0,h14=0,h15=0;
    float last = INF;
    for (int r2 = 0; r2 < KNNK; ++r2) {  // 48 finite values exist -> last finite
      float c0 = md[ 0][ql][h0],  c1 = md[ 1][ql][h1];
      float c2 = md[ 2][ql][h2],  c3 = md[ 3][ql][h3];
      float c4 = md[ 4][ql][h4],  c5 = md[ 5][ql][h5];
      float c6 = md[ 6][ql][h6],  c7 = md[ 7][ql][h7];
      float c8 = md[ 8][ql][h8],  c9 = md[ 9][ql][h9];
      float cA = md[10][ql][h10], cB = md[11][ql][h11];
      float cC = md[12][ql][h12], cD = md[13][ql][h13];
      float cE = md[14][ql][h14], cF = md[15][ql][h15];
      float bv = c0; int bw = 0;
      if (c1 < bv) { bv = c1; bw = 1; }
      if (c2 < bv) { bv = c2; bw = 2; }
      if (c3 < bv) { bv = c3; bw = 3; }
      if (c4 < bv) { bv = c4; bw = 4; }
      if (c5 < bv) { bv = c5; bw = 5; }
      if (c6 < bv) { bv = c6; bw = 6; }
      if (c7 < bv) { bv = c7; bw = 7; }
      if (c8 < bv) { bv = c8; bw = 8; }
      if (c9 < bv) { bv = c9; bw = 9; }
      if (cA < bv) { bv = cA; bw = 10; }
      if (cB < bv) { bv = cB; bw = 11; }
      if (cC < bv) { bv = cC; bw = 12; }
      if (cD < bv) { bv = cD; bw = 13; }
      if (cE < bv) { bv = cE; bw = 14; }
      if (cF < bv) { bv = cF; bw = 15; }
      last = bv;
      h0  += (bw==0);  h1  += (bw==1);  h2  += (bw==2);  h3  += (bw==3);
      h4  += (bw==4);  h5  += (bw==5);  h6  += (bw==6);  h7  += (bw==7);
      h8  += (bw==8);  h9  += (bw==9);  h10 += (bw==10); h11 += (bw==11);
      h12 += (bw==12); h13 += (bw==13); h14 += (bw==14); h15 += (bw==15);
    }
    tau[qg * 64 + ql] = last * 1.00001f;
  }
}

// ---------------------------------------------------------------- s1x: intra-wave-staged screen
// grid 1024 = 256 qg x 4 part-blocks; block 4 waves; wave -> part = pb*4+wv.
// LANE = QUERY. Per 64-candidate window: lane l loads candidate w*64+l
// (coalesced global_load_dwordx4, depth-2 prefetch hidden under ~900cy of
// processing), stages to wave-private LDS; processing reads slot s uniformly
// (ds_read broadcast, conflict-free, in-order, NO barriers). Accept path =
// R16's 6-VALU branchy private-segment append. Candidate order ascending ->
// identical survivors/order to all prior rounds (accept test bit-identical).
__global__ __launch_bounds__(256) void knnconv_s1x(const float4* __restrict__ pos4,
                                                   const float* __restrict__ tau,
                                                   u16* __restrict__ g1,
                                                   u16* __restrict__ gcnt) {
  __shared__ float4 sbuf[4][2][64];      // 8KB wave-private staging
  const int tid  = threadIdx.x;
  const int lane = tid & 63;
  const int wv   = tid >> 6;
  const int qg   = blockIdx.x >> 2;
  const int pb   = blockIdx.x & 3;
  const int part = pb * 4 + wv;          // 0..15, one wave owns one part
  const int q    = qg * 64 + lane;
  const float4 P = pos4[q];
  const float Qx = P.x, Qy = P.y, Qz = P.z;
  const float Qt = 0.5f * (tau[q] - P.w);
  const int cbase = part * PSZ;
  u16* seg = g1 + (q * NSEG + part) * SCAP;
  int cnt = 0;

  float4 r = pos4[cbase + 0 * 64 + lane];
  sbuf[wv][0][lane] = r;
  r = pos4[cbase + 1 * 64 + lane];                 // prefetch window 1
  #pragma unroll 1
  for (int w = 0; w < 16; ++w) {
    const float4* wb = sbuf[wv][w & 1];
    const int gbase = cbase + w * 64;
    #pragma unroll 8
    for (int s = 0; s < 64; ++s) {
      float4 cd = wb[s];                           // uniform ds_read broadcast
      float dot = fmaf(Qx, cd.x, fmaf(Qy, cd.y, Qz * cd.z));
      float lhs = fmaf(0.5f, cd.w, -dot);          // 0.5*cw - dot (bit-identical)
      if (lhs <= Qt) {                             // rare (p ~ 0.5% per lane)
        if (cnt < SCAP) seg[cnt] = (u16)(gbase + s);
        ++cnt;
      }
    }
    if (w < 15) {
      sbuf[wv][(w + 1) & 1][lane] = r;             // vmcnt long satisfied
      if (w < 14) r = pos4[cbase + (w + 2) * 64 + lane];
    }
  }
  gcnt[q * NSEG + part] = (u16)min(cnt, SCAP);
}

// ---------------------------------------------------------------- s2: gather + f64 re-rank
// block = 16 queries x 16 segment-threads; keys[16][256] u64; rank-count.
__global__ __launch_bounds__(256) void knnconv_s2(const float4* __restrict__ pos4,
                                                  const u16* __restrict__ g1,
                                                  const u16* __restrict__ gcnt,
                                                  u16* __restrict__ knn_out) {
  __shared__ u64 keys[16 * 256];         // 32KB
  __shared__ int Tq[16];
  const int tid = threadIdx.x;
  const int iq = tid >> 4, s = tid & 15;
  const int q0 = blockIdx.x * 16;
  const int q = q0 + iq;

  #pragma unroll
  for (int i = 0; i < 16; ++i) keys[i * 256 + tid] = ~0ULL;
  __syncthreads();

  int off = 0, T = 0;
  #pragma unroll
  for (int j = 0; j < NSEG; ++j) {
    int cj = gcnt[q * NSEG + j];
    off += (j < s) ? cj : 0;
    T += cj;
  }
  if (s == 15) Tq[iq] = min(T, 256);
  int myc = gcnt[q * NSEG + s];
  float4 P = pos4[q];
  for (int i = 0; i < myc; ++i) {
    int pos = off + i;
    if (pos >= 256) break;               // deterministic clamp (P ~ 0)
    int cidx = (int)g1[(q * NSEG + s) * SCAP + i];
    float4 C = pos4[cidx];
    double qx = P.x, qy = P.y, qz = P.z;
    double cx = C.x, cy = C.y, cz = C.z;
    double sqq = qx * qx + qy * qy + qz * qz;
    double sqc = cx * cx + cy * cy + cz * cz;
    double dot = qx * cx + qy * cy + qz * cz;
    double d   = (sqq + sqc) - 2.0 * dot;              // exact to ~1e-16
    float df = fmaxf((float)d, 0.0f);                  // one rounding, 6e-8 rel
    keys[iq * 256 + pos] = ((u64)__builtin_bit_cast(u32, df) << 14) | (u32)cidx;
  }
  __syncthreads();

  #pragma unroll 1
  for (int t = 0; t < 16; ++t) {         // uniform per-block iteration
    int T2 = Tq[t];
    if (tid < T2) {
      u64 kj = keys[t * 256 + tid];
      const u64* row = keys + t * 256;
      int r = 0;
      for (int k = 0; k < T2; ++k) r += (row[k] < kj) ? 1 : 0;   // broadcast reads
      if (r < KNNK)
        knn_out[(q0 + t) * KNNK + r] = (u16)(kj & 0x3FFFu);
    }
  }
}

// ---------------------------------------------------------------- W1/W2 -> pre-swizzled bf16 (one-shot)
__global__ __launch_bounds__(256) void knnconv_wprep(const float* __restrict__ W1,
                                                     const float* __restrict__ W2,
                                                     u16* __restrict__ w1bf,
                                                     u16* __restrict__ w2bf) {
  int b = blockIdx.x;
  if (b < 128) {
    int e = b * 256 + threadIdx.x;       // 32768 entries
    int n = e >> 7, kk = e & 127;
    float v;
    if (n < 128) v = W1[(128 + kk) * 128 + n];                              // W1d
    else { int n2 = n - 128; v = W1[kk * 128 + n2] - W1[(128 + kk) * 128 + n2]; }  // W1c-W1d
    w1bf[(n * 256 + ((kk * 2) ^ ((n & 7) << 4))) >> 1] = f2bf(v);
  } else {
    int e = (b - 128) * 256 + threadIdx.x;   // 16384 entries
    int n = e >> 7, kk = e & 127;
    w2bf[(n * 256 + ((kk * 2) ^ ((n & 7) << 4))) >> 1] = f2bf(W2[kk * 128 + n]);
  }
}

// ---------------------------------------------------------------- precompute a = f@W1d (bf16), c = f@(W1c-W1d)+b1 (f32)
__global__ __launch_bounds__(256) void knnconv_prec(const float* __restrict__ feat,
                                                    const u16* __restrict__ w1bf,
                                                    const float* __restrict__ b1,
                                                    u16* __restrict__ a_out,
                                                    float* __restrict__ c_out) {
  __shared__ char sW[65536];   // WT[n=256][k=128] bf16, pre-swizzled (linear copy)
  __shared__ char sF[16384];   // FA[m=64][k=128] bf16, XOR-swizzled
  const int tid = threadIdx.x;
  { // linear coalesced copy of pre-swizzled W1-combined
    const uint4* src = (const uint4*)w1bf;
    uint4* dst = (uint4*)sW;
    #pragma unroll
    for (int r = 0; r < 16; ++r) dst[r * 256 + tid] = src[r * 256 + tid];
  }
  { // stage FA rows (bf16x8 per lane)
    int sub = tid & 15, r0 = tid >> 4;
    int m0 = blockIdx.x * 64;
    for (int rr = 0; rr < 4; ++rr) {
      int r = r0 + rr * 16;
      const float* src = feat + (m0 + r) * 128 + sub * 8;
      float4 v0 = *(const float4*)src;
      float4 v1 = *(const float4*)(src + 4);
      u32 p0 = (u32)f2bf(v0.x) | ((u32)f2bf(v0.y) << 16);
      u32 p1 = (u32)f2bf(v0.z) | ((u32)f2bf(v0.w) << 16);
      u32 p2 = (u32)f2bf(v1.x) | ((u32)f2bf(v1.y) << 16);
      u32 p3 = (u32)f2bf(v1.z) | ((u32)f2bf(v1.w) << 16);
      *(uint4*)(sF + r * 256 + ((sub * 16) ^ ((r & 7) << 4))) = make_uint4(p0, p1, p2, p3);
    }
  }
  __syncthreads();
  const int lane = tid & 63, wv = tid >> 6;
  const int l15 = lane & 15, l4 = lane >> 4;
  f32x4 acc[4][4];
  #pragma unroll
  for (int a = 0; a < 4; ++a)
    #pragma unroll
    for (int b = 0; b < 4; ++b) acc[a][b] = (f32x4){0.f, 0.f, 0.f, 0.f};
  #pragma unroll
  for (int kk = 0; kk < 4; ++kk) {
    int kb = kk * 64 + l4 * 16;
    s16x8 af[4], bfr[4];
    #pragma unroll
    for (int mt = 0; mt < 4; ++mt) {
      int row = mt * 16 + l15;
      af[mt] = *(const s16x8*)(sF + row * 256 + (kb ^ ((row & 7) << 4)));
    }
    #pragma unroll
    for (int nt = 0; nt < 4; ++nt) {
      int n = (wv * 4 + nt) * 16 + l15;
      bfr[nt] = *(const s16x8*)(sW + n * 256 + (kb ^ ((n & 7) << 4)));
    }
    #pragma unroll
    for (int mt = 0; mt < 4; ++mt)
      #pragma unroll
      for (int nt = 0; nt < 4; ++nt)
        acc[mt][nt] = MFMA_BF16(af[mt], bfr[nt], acc[mt][nt], 0, 0, 0);
  }
  int m0 = blockIdx.x * 64;
  #pragma unroll
  for (int nt = 0; nt < 4; ++nt) {
    int n = (wv * 4 + nt) * 16 + l15;
    float bias = (n >= 128) ? b1[n - 128] : 0.0f;
    #pragma unroll
    for (int mt = 0; mt < 4; ++mt)
      #pragma unroll
      for (int r = 0; r < 4; ++r) {
        int m = m0 + mt * 16 + l4 * 4 + r;    // C/D: row=(l>>4)*4+reg, col=l&15
        float v = acc[mt][nt][r];
        if (n < 128) a_out[m * 128 + n] = f2bf(v);
        else         c_out[m * 128 + (n - 128)] = v + bias;
      }
  }
}

// ---------------------------------------------------------------- fused gather + relu + GEMM2 + max
__global__ __launch_bounds__(256) void knnconv_conv(const u16* __restrict__ knn,
                                                    const u16* __restrict__ a_in,
                                                    const float* __restrict__ c_in,
                                                    const u16* __restrict__ w2bf,
                                                    const float* __restrict__ b2,
                                                    float* __restrict__ out) {
  __shared__ char lds[77824];     // [0,40960): A / H2  | [40960,73728): W2T | [73728,77824): c rows
  char* sA = lds;
  char* sW = lds + 40960;
  char* sC = lds + 73728;
  const int tid = threadIdx.x;
  const int q0 = blockIdx.x * 8;

  { // stage c rows for the 8 queries
    int row = tid >> 5, ch4 = (tid & 31) * 4;
    *(float4*)(sC + (row * 128 + ch4) * 4) = *(const float4*)(c_in + (q0 + row) * 128 + ch4);
  }
  __syncthreads();
  { // copy pre-swizzled W2 bf16 (linear copy; layout already swizzled)
    const uint4* src = (const uint4*)w2bf;
    uint4* dst = (uint4*)sW;
    #pragma unroll
    for (int r = 0; r < 8; ++r) dst[r * 256 + tid] = src[r * 256 + tid];
  }
  { // stage A: row r = (query il, neighbor ke): relu(a[idx] + c[il]) -> bf16, swizzled
    int sub = tid & 15, rr = tid >> 4;
    for (int p = 0; p < 10; ++p) {
      int r = p * 16 + rr;
      int il = r / 20;
      int ke = r - il * 20;
      int idx = (int)knn[(q0 + il) * KNNK + ke];
      uint4 av = *(const uint4*)(a_in + idx * 128 + sub * 8);
      float4 c0 = *(const float4*)(sC + (il * 128 + sub * 8) * 4);
      float4 c1 = *(const float4*)(sC + (il * 128 + sub * 8 + 4) * 4);
      float h0 = fmaxf(bf2f((u16)(av.x & 0xFFFF)) + c0.x, 0.f);
      float h1 = fmaxf(bf2f((u16)(av.x >> 16))    + c0.y, 0.f);
      float h2 = fmaxf(bf2f((u16)(av.y & 0xFFFF)) + c0.z, 0.f);
      float h3 = fmaxf(bf2f((u16)(av.y >> 16))    + c0.w, 0.f);
      float h4 = fmaxf(bf2f((u16)(av.z & 0xFFFF)) + c1.x, 0.f);
      float h5 = fmaxf(bf2f((u16)(av.z >> 16))    + c1.y, 0.f);
      float h6 = fmaxf(bf2f((u16)(av.w & 0xFFFF)) + c1.z, 0.f);
      float h7 = fmaxf(bf2f((u16)(av.w >> 16))    + c1.w, 0.f);
      u32 p0 = (u32)f2bf(h0) | ((u32)f2bf(h1) << 16);
      u32 p1 = (u32)f2bf(h2) | ((u32)f2bf(h3) << 16);
      u32 p2 = (u32)f2bf(h4) | ((u32)f2bf(h5) << 16);
      u32 p3 = (u32)f2bf(h6) | ((u32)f2bf(h7) << 16);
      *(uint4*)(sA + r * 256 + ((sub * 16) ^ ((r & 7) << 4))) = make_uint4(p0, p1, p2, p3);
    }
  }
  __syncthreads();
  const int lane = tid & 63, wv = tid >> 6;
  const int l15 = lane & 15, l4 = lane >> 4;
  f32x4 acc[10][2];
  #pragma unroll
  for (int mt = 0; mt < 10; ++mt) { acc[mt][0] = (f32x4){0,0,0,0}; acc[mt][1] = (f32x4){0,0,0,0}; }
  #pragma unroll
  for (int kk = 0; kk < 4; ++kk) {
    int kb = kk * 64 + l4 * 16;
    s16x8 b0, b1r;
    { int n = (wv * 2 + 0) * 16 + l15; b0  = *(const s16x8*)(sW + n * 256 + (kb ^ ((n & 7) << 4))); }
    { int n = (wv * 2 + 1) * 16 + l15; b1r = *(const s16x8*)(sW + n * 256 + (kb ^ ((n & 7) << 4))); }
    #pragma unroll
    for (int mt = 0; mt < 10; ++mt) {
      int row = mt * 16 + l15;
      s16x8 a = *(const s16x8*)(sA + row * 256 + (kb ^ ((row & 7) << 4)));
      acc[mt][0] = MFMA_BF16(a, b0,  acc[mt][0], 0, 0, 0);
      acc[mt][1] = MFMA_BF16(a, b1r, acc[mt][1], 0, 0, 0);
    }
  }
  __syncthreads();              // all waves done reading A before H2 overwrite
  #pragma unroll
  for (int mt = 0; mt < 10; ++mt)
    #pragma unroll
    for (int nt = 0; nt < 2; ++nt) {
      int n = (wv * 2 + nt) * 16 + l15;
      #pragma unroll
      for (int r = 0; r < 4; ++r) {
        int row = mt * 16 + l4 * 4 + r;
        *(u16*)(sA + row * 256 + n * 2) = f2bf(acc[mt][nt][r]);  // H2, plain layout
      }
    }
  __syncthreads();
  { // max over 20 neighbors + b2
    int ch = tid & 127, g = tid >> 7;
    float bias = b2[ch];
    for (int pp = 0; pp < 4; ++pp) {
      int qq = pp * 2 + g;
      float mx = -__builtin_inff();
      #pragma unroll
      for (int e = 0; e < KNNK; ++e)
        mx = fmaxf(mx, bf2f(*(const u16*)(sA + (qq * 20 + e) * 256 + ch * 2)));
      out[(q0 + qq) * 128 + ch] = mx + bias;
    }
  }
}

// ---------------------------------------------------------------- launch
extern "C" void kernel_launch(void* const* d_in, const int* in_sizes, int n_in,
                              void* d_out, int out_size, void* d_ws, size_t ws_size,
                              hipStream_t stream) {
  const float* pos  = (const float*)d_in[0];
  const float* feat = (const float*)d_in[1];
  const float* W1   = (const float*)d_in[2];
  const float* b1   = (const float*)d_in[3];
  const float* W2   = (const float*)d_in[4];
  const float* b2   = (const float*)d_in[5];
  float* out = (float*)d_out;
  char* ws = (char*)d_ws;
  // ws layout (aliases noted):
  //  [0,256K)              pos4 (prep..s2)        -> w1bf 64KB + w2bf 32KB (wprep..conv)
  //  [256K,917504)         knn u16 (s2..conv)
  //  [917504,13500416)     g1 [16384][16][24] u16 (s1x..s2) -> a_buf 4MB + c_buf 8MB (prec..conv)
  //  [13500416,14024704)   gcnt [16384][16] u16 (s1x..s2)
  //  [14024704,14090240)   tau [16384] f32 (s0..s1x)
  float4* pos4  = (float4*)ws;
  u16*    w1bf  = (u16*)ws;
  u16*    w2bf  = (u16*)(ws + 65536);
  u16*    knn   = (u16*)(ws + 262144);
  u16*    g1    = (u16*)(ws + 917504);
  u16*    a_buf = (u16*)(ws + 917504);
  float*  c_buf = (float*)(ws + 5111808);
  u16*    gcnt  = (u16*)(ws + 13500416);
  float*  tau   = (float*)(ws + 14024704);
  if (ws_size < 14090240) return;   // insufficient scratch (would corrupt)

  knnconv_prep<<<64, 256, 0, stream>>>(pos, pos4);
  knnconv_s0<<<256, 1024, 0, stream>>>(pos4, tau);
  knnconv_s1x<<<1024, 256, 0, stream>>>(pos4, tau, g1, gcnt);
  knnconv_s2<<<1024, 256, 0, stream>>>(pos4, g1, gcnt, knn);
  knnconv_wprep<<<192, 256, 0, stream>>>(W1, W2, w1bf, w2bf);          // overwrites pos4 (dead)
  knnconv_prec<<<256, 256, 0, stream>>>(feat, w1bf, b1, a_buf, c_buf); // overwrites g1 (dead)
  knnconv_conv<<<2048, 256, 0, stream>>>(knn, a_buf, c_buf, w2bf, b2, out);
}

// Round 21
// 207.141 us; speedup vs baseline: 1.2208x; 1.0620x over previous
//
#include <hip/hip_runtime.h>

typedef unsigned short u16;
typedef unsigned int   u32;
typedef unsigned long long u64;
typedef short s16x8 __attribute__((ext_vector_type(8)));   // 8 x bf16 bits (4 VGPRs)
typedef float f32x4 __attribute__((ext_vector_type(4)));   // MFMA accumulator

#define NPTS   16384
#define KNNK   20
#define SLOTS3 12      // s0 stack slots (trigger 4, growth <= 8 => max 11)
#define TRIG3  4
#define NSEG   16      // s1x candidate parts per query
#define PSZ    1024    // candidates per part
#define SCAP   24      // survivor cap per (query, part)  [E~5; P(overflow) ~1e-4 total]

#define MFMA_BF16 __builtin_amdgcn_mfma_f32_16x16x32_bf16

__device__ __forceinline__ u16 f2bf(float x) {
  u32 u = __builtin_bit_cast(u32, x);
  u32 r = (u + 0x7FFFu + ((u >> 16) & 1u)) >> 16;   // RNE
  return (u16)r;
}
__device__ __forceinline__ float bf2f(u16 b) {
  u32 u = ((u32)b) << 16;
  return __builtin_bit_cast(float, u);
}
__device__ __forceinline__ float dist2(float4 qp, float4 cd) {
  float dot = fmaf(qp.x, cd.x, fmaf(qp.y, cd.y, qp.z * cd.z));
  return fmaf(-2.0f, dot, qp.w + cd.w);
}

// ---------------------------------------------------------------- prep: pos4 = (x,y,z,|p|^2)
__global__ __launch_bounds__(256) void knnconv_prep(const float* __restrict__ pos,
                                                    float4* __restrict__ pos4) {
  int i = blockIdx.x * 256 + threadIdx.x;
  float x = pos[i * 3 + 0], y = pos[i * 3 + 1], z = pos[i * 3 + 2];
  float sq = (x * x + y * y) + z * z;    // f32 screen only; f64 re-rank decides final set
  pos4[i] = make_float4(x, y, z, sq);
}

// ---------------------------------------------------------------- s0: sample threshold
// grid 256; block 1024 = 16 waves; lane = query. Wave wv scans 256 samples
// (every 4th point) in 4 windows of 64: lane l loads sample w*64+l (coalesced,
// depth-2 prefetch), stages to wave-private LDS, processing reads slot s
// uniformly (broadcast, conflict-free, NO barriers -- intra-wave lgkmcnt).
// Sample order identical to prior rounds -> bit-identical tau. Top-3 lazy
// stack + 16-way merge -> tau = 20th of 48-value union (provable superset).
__global__ __launch_bounds__(1024) void knnconv_s0(const float4* __restrict__ pos4,
                                                   float* __restrict__ tau) {
  __shared__ float sd[SLOTS3 * 1024];    // 48KB per-lane stacks
  __shared__ float md[16][64][4];        // 16KB sorted top-3 + INF sentinel
  __shared__ float4 stg[16][2][64];      // 32KB wave-private staging
  const int tid  = threadIdx.x;
  const int lane = tid & 63;
  const int wv   = tid >> 6;             // 0..15
  const int qg   = blockIdx.x;
  const int q    = qg * 64 + lane;
  const float4 qp = pos4[q];
  const float INF = __builtin_inff();

  float t0v = INF, t1v = INF, t2v = INF; // sorted top-3 in registers
  float thrF = INF;
  int cnt = 0;
  const int kbase = wv * 256;            // sample index base (sample i -> point 4i)

#define FLUSH3()                                                      \
  { _Pragma("unroll 1")                                               \
    for (int e = 0; e < SLOTS3; e += 2) {                             \
      if (!__any(e < cnt)) break;                                     \
      float lo = (e     < cnt) ? sd[e * 1024 + tid]       : INF;      \
      float hi = (e + 1 < cnt) ? sd[(e + 1) * 1024 + tid] : INF;      \
      float a_ = fminf(lo, hi), b_ = fmaxf(lo, hi);                   \
      lo = a_; hi = b_;                                               \
      { float m = fminf(lo, t0v), x = fmaxf(lo, t0v);                 \
        t0v = m; lo = fminf(x, hi); hi = fmaxf(x, hi); }              \
      { float m = fminf(lo, t1v), x = fmaxf(lo, t1v);                 \
        t1v = m; lo = fminf(x, hi); hi = fmaxf(x, hi); }              \
      t2v = fminf(lo, t2v);                                           \
    }                                                                 \
    thrF = t2v;                                                       \
    cnt = 0; }

  float4 r = pos4[(kbase + 0 * 64 + lane) * 4];
  stg[wv][0][lane] = r;
  r = pos4[(kbase + 1 * 64 + lane) * 4];           // prefetch window 1
  #pragma unroll 1
  for (int w = 0; w < 4; ++w) {
    const float4* wb = stg[wv][w & 1];
    #pragma unroll 1
    for (int g8 = 0; g8 < 64; g8 += 8) {
      #pragma unroll
      for (int u = 0; u < 8; ++u) {
        float d2 = dist2(qp, wb[g8 + u]);          // uniform ds_read broadcast
        sd[cnt * 1024 + tid] = d2;                 // unconditional (slot <= 10)
        cnt += (d2 < thrF) ? 1 : 0;
      }
      if (__any(cnt >= TRIG3)) { FLUSH3(); }
    }
    if (w < 3) {
      stg[wv][(w + 1) & 1][lane] = r;              // vmcnt long satisfied
      if (w < 2) r = pos4[(kbase + (w + 2) * 64 + lane) * 4];
    }
  }
  FLUSH3();

  md[wv][lane][0] = t0v;
  md[wv][lane][1] = t1v;
  md[wv][lane][2] = t2v;
  md[wv][lane][3] = INF;                 // sentinel: heads may clamp at 3
  __syncthreads();

  if (tid < 64) {                        // 16-way merge of top-3 lists, take 20th
    int ql = tid;
    int h0=0,h1=0,h2=0,h3=0,h4=0,h5=0,h6=0,h7=0;
    int h8=0,h9=0,h10=0,h11=0,h12=0,h13=0,h14=0,h15=0;
    float last = INF;
    for (int r2 = 0; r2 < KNNK; ++r2) {  // 48 finite values exist -> last finite
      float c0 = md[ 0][ql][h0],  c1 = md[ 1][ql][h1];
      float c2 = md[ 2][ql][h2],  c3 = md[ 3][ql][h3];
      float c4 = md[ 4][ql][h4],  c5 = md[ 5][ql][h5];
      float c6 = md[ 6][ql][h6],  c7 = md[ 7][ql][h7];
      float c8 = md[ 8][ql][h8],  c9 = md[ 9][ql][h9];
      float cA = md[10][ql][h10], cB = md[11][ql][h11];
      float cC = md[12][ql][h12], cD = md[13][ql][h13];
      float cE = md[14][ql][h14], cF = md[15][ql][h15];
      float bv = c0; int bw = 0;
      if (c1 < bv) { bv = c1; bw = 1; }
      if (c2 < bv) { bv = c2; bw = 2; }
      if (c3 < bv) { bv = c3; bw = 3; }
      if (c4 < bv) { bv = c4; bw = 4; }
      if (c5 < bv) { bv = c5; bw = 5; }
      if (c6 < bv) { bv = c6; bw = 6; }
      if (c7 < bv) { bv = c7; bw = 7; }
      if (c8 < bv) { bv = c8; bw = 8; }
      if (c9 < bv) { bv = c9; bw = 9; }
      if (cA < bv) { bv = cA; bw = 10; }
      if (cB < bv) { bv = cB; bw = 11; }
      if (cC < bv) { bv = cC; bw = 12; }
      if (cD < bv) { bv = cD; bw = 13; }
      if (cE < bv) { bv = cE; bw = 14; }
      if (cF < bv) { bv = cF; bw = 15; }
      last = bv;
      h0  += (bw==0);  h1  += (bw==1);  h2  += (bw==2);  h3  += (bw==3);
      h4  += (bw==4);  h5  += (bw==5);  h6  += (bw==6);  h7  += (bw==7);
      h8  += (bw==8);  h9  += (bw==9);  h10 += (bw==10); h11 += (bw==11);
      h12 += (bw==12); h13 += (bw==13); h14 += (bw==14); h15 += (bw==15);
    }
    tau[qg * 64 + ql] = last * 1.00001f;
  }
}

// ---------------------------------------------------------------- s1x: scalar-broadcast screen, batch-16
// grid 1024 = 256 qg x 4 part-blocks; block 4 waves; wave -> part = pb*4+wv.
// LANE = QUERY; candidates via wave-uniform scalar loads in SERIAL BATCHES OF
// 16 (256B -> s_load_dwordx16 x4). SMEM returns are OoO so any use forces a
// full lgkmcnt(0) drain (~550cy measured, R16 pm); amortizing it over 192cy of
// compute (vs 96 at batch 8) puts 4 waves/SIMD at ~100% duty. Survivors ->
// private per-(q,part) segment: no atomics, no LDS. Accept test/order
// bit-identical to all prior rounds.
__global__ __launch_bounds__(256) void knnconv_s1x(const float4* __restrict__ pos4,
                                                   const float* __restrict__ tau,
                                                   u16* __restrict__ g1,
                                                   u16* __restrict__ gcnt) {
  const int tid  = threadIdx.x;
  const int lane = tid & 63;
  const int wv   = __builtin_amdgcn_readfirstlane(tid >> 6);   // uniform -> SGPR
  const int qg   = blockIdx.x >> 2;
  const int pb   = blockIdx.x & 3;
  const int part = pb * 4 + wv;          // 0..15, one wave owns one part
  const int q    = qg * 64 + lane;
  const float4 P = pos4[q];
  const float Qx = P.x, Qy = P.y, Qz = P.z;
  const float Qt = 0.5f * (tau[q] - P.w);
  const int cbase = part * PSZ;
  const float4* cp = pos4 + cbase;       // SGPR base -> s_load candidates
  u16* seg = g1 + (q * NSEG + part) * SCAP;
  int cnt = 0;

  #pragma unroll 1
  for (int t0 = 0; t0 < PSZ; t0 += 16) {
    float4 c[16];
    #pragma unroll
    for (int u = 0; u < 16; ++u) c[u] = cp[t0 + u];    // wave-uniform scalar loads
    #pragma unroll
    for (int u = 0; u < 16; ++u) {
      float dot = fmaf(Qx, c[u].x, fmaf(Qy, c[u].y, Qz * c[u].z));
      float lhs = fmaf(0.5f, c[u].w, -dot);            // 0.5*cw - dot
      if (lhs <= Qt) {                                 // rare (p ~ 0.5% per lane)
        if (cnt < SCAP) seg[cnt] = (u16)(cbase + t0 + u);
        ++cnt;
      }
    }
  }
  gcnt[q * NSEG + part] = (u16)min(cnt, SCAP);
}

// ---------------------------------------------------------------- s2: gather + f64 re-rank
// block = 16 queries x 16 segment-threads; keys[16][256] u64; rank-count.
__global__ __launch_bounds__(256) void knnconv_s2(const float4* __restrict__ pos4,
                                                  const u16* __restrict__ g1,
                                                  const u16* __restrict__ gcnt,
                                                  u16* __restrict__ knn_out) {
  __shared__ u64 keys[16 * 256];         // 32KB
  __shared__ int Tq[16];
  const int tid = threadIdx.x;
  const int iq = tid >> 4, s = tid & 15;
  const int q0 = blockIdx.x * 16;
  const int q = q0 + iq;

  #pragma unroll
  for (int i = 0; i < 16; ++i) keys[i * 256 + tid] = ~0ULL;
  __syncthreads();

  int off = 0, T = 0;
  #pragma unroll
  for (int j = 0; j < NSEG; ++j) {
    int cj = gcnt[q * NSEG + j];
    off += (j < s) ? cj : 0;
    T += cj;
  }
  if (s == 15) Tq[iq] = min(T, 256);
  int myc = gcnt[q * NSEG + s];
  float4 P = pos4[q];
  for (int i = 0; i < myc; ++i) {
    int pos = off + i;
    if (pos >= 256) break;               // deterministic clamp (P ~ 0)
    int cidx = (int)g1[(q * NSEG + s) * SCAP + i];
    float4 C = pos4[cidx];
    double qx = P.x, qy = P.y, qz = P.z;
    double cx = C.x, cy = C.y, cz = C.z;
    double sqq = qx * qx + qy * qy + qz * qz;
    double sqc = cx * cx + cy * cy + cz * cz;
    double dot = qx * cx + qy * cy + qz * cz;
    double d   = (sqq + sqc) - 2.0 * dot;              // exact to ~1e-16
    float df = fmaxf((float)d, 0.0f);                  // one rounding, 6e-8 rel
    keys[iq * 256 + pos] = ((u64)__builtin_bit_cast(u32, df) << 14) | (u32)cidx;
  }
  __syncthreads();

  #pragma unroll 1
  for (int t = 0; t < 16; ++t) {         // uniform per-block iteration
    int T2 = Tq[t];
    if (tid < T2) {
      u64 kj = keys[t * 256 + tid];
      const u64* row = keys + t * 256;
      int r = 0;
      for (int k = 0; k < T2; ++k) r += (row[k] < kj) ? 1 : 0;   // broadcast reads
      if (r < KNNK)
        knn_out[(q0 + t) * KNNK + r] = (u16)(kj & 0x3FFFu);
    }
  }
}

// ---------------------------------------------------------------- W1/W2 -> pre-swizzled bf16 (one-shot)
__global__ __launch_bounds__(256) void knnconv_wprep(const float* __restrict__ W1,
                                                     const float* __restrict__ W2,
                                                     u16* __restrict__ w1bf,
                                                     u16* __restrict__ w2bf) {
  int b = blockIdx.x;
  if (b < 128) {
    int e = b * 256 + threadIdx.x;       // 32768 entries
    int n = e >> 7, kk = e & 127;
    float v;
    if (n < 128) v = W1[(128 + kk) * 128 + n];                              // W1d
    else { int n2 = n - 128; v = W1[kk * 128 + n2] - W1[(128 + kk) * 128 + n2]; }  // W1c-W1d
    w1bf[(n * 256 + ((kk * 2) ^ ((n & 7) << 4))) >> 1] = f2bf(v);
  } else {
    int e = (b - 128) * 256 + threadIdx.x;   // 16384 entries
    int n = e >> 7, kk = e & 127;
    w2bf[(n * 256 + ((kk * 2) ^ ((n & 7) << 4))) >> 1] = f2bf(W2[kk * 128 + n]);
  }
}

// ---------------------------------------------------------------- precompute a = f@W1d (bf16), c = f@(W1c-W1d)+b1 (f32)
__global__ __launch_bounds__(256) void knnconv_prec(const float* __restrict__ feat,
                                                    const u16* __restrict__ w1bf,
                                                    const float* __restrict__ b1,
                                                    u16* __restrict__ a_out,
                                                    float* __restrict__ c_out) {
  __shared__ char sW[65536];   // WT[n=256][k=128] bf16, pre-swizzled (linear copy)
  __shared__ char sF[16384];   // FA[m=64][k=128] bf16, XOR-swizzled
  const int tid = threadIdx.x;
  { // linear coalesced copy of pre-swizzled W1-combined
    const uint4* src = (const uint4*)w1bf;
    uint4* dst = (uint4*)sW;
    #pragma unroll
    for (int r = 0; r < 16; ++r) dst[r * 256 + tid] = src[r * 256 + tid];
  }
  { // stage FA rows (bf16x8 per lane)
    int sub = tid & 15, r0 = tid >> 4;
    int m0 = blockIdx.x * 64;
    for (int rr = 0; rr < 4; ++rr) {
      int r = r0 + rr * 16;
      const float* src = feat + (m0 + r) * 128 + sub * 8;
      float4 v0 = *(const float4*)src;
      float4 v1 = *(const float4*)(src + 4);
      u32 p0 = (u32)f2bf(v0.x) | ((u32)f2bf(v0.y) << 16);
      u32 p1 = (u32)f2bf(v0.z) | ((u32)f2bf(v0.w) << 16);
      u32 p2 = (u32)f2bf(v1.x) | ((u32)f2bf(v1.y) << 16);
      u32 p3 = (u32)f2bf(v1.z) | ((u32)f2bf(v1.w) << 16);
      *(uint4*)(sF + r * 256 + ((sub * 16) ^ ((r & 7) << 4))) = make_uint4(p0, p1, p2, p3);
    }
  }
  __syncthreads();
  const int lane = tid & 63, wv = tid >> 6;
  const int l15 = lane & 15, l4 = lane >> 4;
  f32x4 acc[4][4];
  #pragma unroll
  for (int a = 0; a < 4; ++a)
    #pragma unroll
    for (int b = 0; b < 4; ++b) acc[a][b] = (f32x4){0.f, 0.f, 0.f, 0.f};
  #pragma unroll
  for (int kk = 0; kk < 4; ++kk) {
    int kb = kk * 64 + l4 * 16;
    s16x8 af[4], bfr[4];
    #pragma unroll
    for (int mt = 0; mt < 4; ++mt) {
      int row = mt * 16 + l15;
      af[mt] = *(const s16x8*)(sF + row * 256 + (kb ^ ((row & 7) << 4)));
    }
    #pragma unroll
    for (int nt = 0; nt < 4; ++nt) {
      int n = (wv * 4 + nt) * 16 + l15;
      bfr[nt] = *(const s16x8*)(sW + n * 256 + (kb ^ ((n & 7) << 4)));
    }
    #pragma unroll
    for (int mt = 0; mt < 4; ++mt)
      #pragma unroll
      for (int nt = 0; nt < 4; ++nt)
        acc[mt][nt] = MFMA_BF16(af[mt], bfr[nt], acc[mt][nt], 0, 0, 0);
  }
  int m0 = blockIdx.x * 64;
  #pragma unroll
  for (int nt = 0; nt < 4; ++nt) {
    int n = (wv * 4 + nt) * 16 + l15;
    float bias = (n >= 128) ? b1[n - 128] : 0.0f;
    #pragma unroll
    for (int mt = 0; mt < 4; ++mt)
      #pragma unroll
      for (int r = 0; r < 4; ++r) {
        int m = m0 + mt * 16 + l4 * 4 + r;    // C/D: row=(l>>4)*4+reg, col=l&15
        float v = acc[mt][nt][r];
        if (n < 128) a_out[m * 128 + n] = f2bf(v);
        else         c_out[m * 128 + (n - 128)] = v + bias;
      }
  }
}

// ---------------------------------------------------------------- fused gather + relu + GEMM2 + max
__global__ __launch_bounds__(256) void knnconv_conv(const u16* __restrict__ knn,
                                                    const u16* __restrict__ a_in,
                                                    const float* __restrict__ c_in,
                                                    const u16* __restrict__ w2bf,
                                                    const float* __restrict__ b2,
                                                    float* __restrict__ out) {
  __shared__ char lds[77824];     // [0,40960): A / H2  | [40960,73728): W2T | [73728,77824): c rows
  char* sA = lds;
  char* sW = lds + 40960;
  char* sC = lds + 73728;
  const int tid = threadIdx.x;
  const int q0 = blockIdx.x * 8;

  { // stage c rows for the 8 queries
    int row = tid >> 5, ch4 = (tid & 31) * 4;
    *(float4*)(sC + (row * 128 + ch4) * 4) = *(const float4*)(c_in + (q0 + row) * 128 + ch4);
  }
  __syncthreads();
  { // copy pre-swizzled W2 bf16 (linear copy; layout already swizzled)
    const uint4* src = (const uint4*)w2bf;
    uint4* dst = (uint4*)sW;
    #pragma unroll
    for (int r = 0; r < 8; ++r) dst[r * 256 + tid] = src[r * 256 + tid];
  }
  { // stage A: row r = (query il, neighbor ke): relu(a[idx] + c[il]) -> bf16, swizzled
    int sub = tid & 15, rr = tid >> 4;
    for (int p = 0; p < 10; ++p) {
      int r = p * 16 + rr;
      int il = r / 20;
      int ke = r - il * 20;
      int idx = (int)knn[(q0 + il) * KNNK + ke];
      uint4 av = *(const uint4*)(a_in + idx * 128 + sub * 8);
      float4 c0 = *(const float4*)(sC + (il * 128 + sub * 8) * 4);
      float4 c1 = *(const float4*)(sC + (il * 128 + sub * 8 + 4) * 4);
      float h0 = fmaxf(bf2f((u16)(av.x & 0xFFFF)) + c0.x, 0.f);
      float h1 = fmaxf(bf2f((u16)(av.x >> 16))    + c0.y, 0.f);
      float h2 = fmaxf(bf2f((u16)(av.y & 0xFFFF)) + c0.z, 0.f);
      float h3 = fmaxf(bf2f((u16)(av.y >> 16))    + c0.w, 0.f);
      float h4 = fmaxf(bf2f((u16)(av.z & 0xFFFF)) + c1.x, 0.f);
      float h5 = fmaxf(bf2f((u16)(av.z >> 16))    + c1.y, 0.f);
      float h6 = fmaxf(bf2f((u16)(av.w & 0xFFFF)) + c1.z, 0.f);
      float h7 = fmaxf(bf2f((u16)(av.w >> 16))    + c1.w, 0.f);
      u32 p0 = (u32)f2bf(h0) | ((u32)f2bf(h1) << 16);
      u32 p1 = (u32)f2bf(h2) | ((u32)f2bf(h3) << 16);
      u32 p2 = (u32)f2bf(h4) | ((u32)f2bf(h5) << 16);
      u32 p3 = (u32)f2bf(h6) | ((u32)f2bf(h7) << 16);
      *(uint4*)(sA + r * 256 + ((sub * 16) ^ ((r & 7) << 4))) = make_uint4(p0, p1, p2, p3);
    }
  }
  __syncthreads();
  const int lane = tid & 63, wv = tid >> 6;
  const int l15 = lane & 15, l4 = lane >> 4;
  f32x4 acc[10][2];
  #pragma unroll
  for (int mt = 0; mt < 10; ++mt) { acc[mt][0] = (f32x4){0,0,0,0}; acc[mt][1] = (f32x4){0,0,0,0}; }
  #pragma unroll
  for (int kk = 0; kk < 4; ++kk) {
    int kb = kk * 64 + l4 * 16;
    s16x8 b0, b1r;
    { int n = (wv * 2 + 0) * 16 + l15; b0  = *(const s16x8*)(sW + n * 256 + (kb ^ ((n & 7) << 4))); }
    { int n = (wv * 2 + 1) * 16 + l15; b1r = *(const s16x8*)(sW + n * 256 + (kb ^ ((n & 7) << 4))); }
    #pragma unroll
    for (int mt = 0; mt < 10; ++mt) {
      int row = mt * 16 + l15;
      s16x8 a = *(const s16x8*)(sA + row * 256 + (kb ^ ((row & 7) << 4)));
      acc[mt][0] = MFMA_BF16(a, b0,  acc[mt][0], 0, 0, 0);
      acc[mt][1] = MFMA_BF16(a, b1r, acc[mt][1], 0, 0, 0);
    }
  }
  __syncthreads();              // all waves done reading A before H2 overwrite
  #pragma unroll
  for (int mt = 0; mt < 10; ++mt)
    #pragma unroll
    for (int nt = 0; nt < 2; ++nt) {
      int n = (wv * 2 + nt) * 16 + l15;
      #pragma unroll
      for (int r = 0; r < 4; ++r) {
        int row = mt * 16 + l4 * 4 + r;
        *(u16*)(sA + row * 256 + n * 2) = f2bf(acc[mt][nt][r]);  // H2, plain layout
      }
    }
  __syncthreads();
  { // max over 20 neighbors + b2
    int ch = tid & 127, g = tid >> 7;
    float bias = b2[ch];
    for (int pp = 0; pp < 4; ++pp) {
      int qq = pp * 2 + g;
      float mx = -__builtin_inff();
      #pragma unroll
      for (int e = 0; e < KNNK; ++e)
        mx = fmaxf(mx, bf2f(*(const u16*)(sA + (qq * 20 + e) * 256 + ch * 2)));
      out[(q0 + qq) * 128 + ch] = mx + bias;
    }
  }
}

// ---------------------------------------------------------------- launch
extern "C" void kernel_launch(void* const* d_in, const int* in_sizes, int n_in,
                              void* d_out, int out_size, void* d_ws, size_t ws_size,
                              hipStream_t stream) {
  const float* pos  = (const float*)d_in[0];
  const float* feat = (const float*)d_in[1];
  const float* W1   = (const float*)d_in[2];
  const float* b1   = (const float*)d_in[3];
  const float* W2   = (const float*)d_in[4];
  const float* b2   = (const float*)d_in[5];
  float* out = (float*)d_out;
  char* ws = (char*)d_ws;
  // ws layout (aliases noted):
  //  [0,256K)              pos4 (prep..s2)        -> w1bf 64KB + w2bf 32KB (wprep..conv)
  //  [256K,917504)         knn u16 (s2..conv)
  //  [917504,13500416)     g1 [16384][16][24] u16 (s1x..s2) -> a_buf 4MB + c_buf 8MB (prec..conv)
  //  [13500416,14024704)   gcnt [16384][16] u16 (s1x..s2)
  //  [14024704,14090240)   tau [16384] f32 (s0..s1x)
  float4* pos4  = (float4*)ws;
  u16*    w1bf  = (u16*)ws;
  u16*    w2bf  = (u16*)(ws + 65536);
  u16*    knn   = (u16*)(ws + 262144);
  u16*    g1    = (u16*)(ws + 917504);
  u16*    a_buf = (u16*)(ws + 917504);
  float*  c_buf = (float*)(ws + 5111808);
  u16*    gcnt  = (u16*)(ws + 13500416);
  float*  tau   = (float*)(ws + 14024704);
  if (ws_size < 14090240) return;   // insufficient scratch (would corrupt)

  knnconv_prep<<<64, 256, 0, stream>>>(pos, pos4);
  knnconv_s0<<<256, 1024, 0, stream>>>(pos4, tau);
  knnconv_s1x<<<1024, 256, 0, stream>>>(pos4, tau, g1, gcnt);
  knnconv_s2<<<1024, 256, 0, stream>>>(pos4, g1, gcnt, knn);
  knnconv_wprep<<<192, 256, 0, stream>>>(W1, W2, w1bf, w2bf);          // overwrites pos4 (dead)
  knnconv_prec<<<256, 256, 0, stream>>>(feat, w1bf, b1, a_buf, c_buf); // overwrites g1 (dead)
  knnconv_conv<<<2048, 256, 0, stream>>>(knn, a_buf, c_buf, w2bf, b2, out);
}

// Round 22
// 196.128 us; speedup vs baseline: 1.2893x; 1.0562x over previous
//
#include <hip/hip_runtime.h>

typedef unsigned short u16;
typedef unsigned int   u32;
typedef unsigned long long u64;
typedef short s16x8 __attribute__((ext_vector_type(8)));   // 8 x bf16 bits (4 VGPRs)
typedef float f32x4 __attribute__((ext_vector_type(4)));   // MFMA accumulator

#define NPTS   16384
#define KNNK   20
#define SLOTS3 12      // s0 stack slots (trigger 4, growth <= 8 => max 11)
#define TRIG3  4
#define NSEG   16      // s1x candidate parts per query
#define PSZ    1024    // candidates per part
#define SCAP   24      // survivor cap per (query, part)  [E~5; P(overflow) ~1e-4 total]

#define MFMA_BF16 __builtin_amdgcn_mfma_f32_16x16x32_bf16

__device__ __forceinline__ u16 f2bf(float x) {
  u32 u = __builtin_bit_cast(u32, x);
  u32 r = (u + 0x7FFFu + ((u >> 16) & 1u)) >> 16;   // RNE
  return (u16)r;
}
__device__ __forceinline__ float bf2f(u16 b) {
  u32 u = ((u32)b) << 16;
  return __builtin_bit_cast(float, u);
}
__device__ __forceinline__ float dist2(float4 qp, float4 cd) {
  float dot = fmaf(qp.x, cd.x, fmaf(qp.y, cd.y, qp.z * cd.z));
  return fmaf(-2.0f, dot, qp.w + cd.w);
}

// ---------------------------------------------------------------- prep: pos4 = (x,y,z,|p|^2)
__global__ __launch_bounds__(256) void knnconv_prep(const float* __restrict__ pos,
                                                    float4* __restrict__ pos4) {
  int i = blockIdx.x * 256 + threadIdx.x;
  float x = pos[i * 3 + 0], y = pos[i * 3 + 1], z = pos[i * 3 + 2];
  float sq = (x * x + y * y) + z * z;    // f32 screen only; f64 re-rank decides final set
  pos4[i] = make_float4(x, y, z, sq);
}

// ---------------------------------------------------------------- s0: sample threshold
// grid 256; block 1024 = 16 waves; lane = query. Wave wv scans 256 samples
// (every 4th point) in 4 windows of 64: lane l loads sample w*64+l (coalesced,
// depth-2 prefetch), stages to wave-private LDS, processing reads slot s
// uniformly (broadcast, conflict-free, NO barriers -- intra-wave lgkmcnt).
// Top-3 lazy stack + 16-way merge -> tau = 20th of 48-value union (provable
// superset bound: >=20 full points within tau).
__global__ __launch_bounds__(1024) void knnconv_s0(const float4* __restrict__ pos4,
                                                   float* __restrict__ tau) {
  __shared__ float sd[SLOTS3 * 1024];    // 48KB per-lane stacks
  __shared__ float md[16][64][4];        // 16KB sorted top-3 + INF sentinel
  __shared__ float4 stg[16][2][64];      // 32KB wave-private staging
  const int tid  = threadIdx.x;
  const int lane = tid & 63;
  const int wv   = tid >> 6;             // 0..15
  const int qg   = blockIdx.x;
  const int q    = qg * 64 + lane;
  const float4 qp = pos4[q];
  const float INF = __builtin_inff();

  float t0v = INF, t1v = INF, t2v = INF; // sorted top-3 in registers
  float thrF = INF;
  int cnt = 0;
  const int kbase = wv * 256;            // sample index base (sample i -> point 4i)

#define FLUSH3()                                                      \
  { _Pragma("unroll 1")                                               \
    for (int e = 0; e < SLOTS3; e += 2) {                             \
      if (!__any(e < cnt)) break;                                     \
      float lo = (e     < cnt) ? sd[e * 1024 + tid]       : INF;      \
      float hi = (e + 1 < cnt) ? sd[(e + 1) * 1024 + tid] : INF;      \
      float a_ = fminf(lo, hi), b_ = fmaxf(lo, hi);                   \
      lo = a_; hi = b_;                                               \
      { float m = fminf(lo, t0v), x = fmaxf(lo, t0v);                 \
        t0v = m; lo = fminf(x, hi); hi = fmaxf(x, hi); }              \
      { float m = fminf(lo, t1v), x = fmaxf(lo, t1v);                 \
        t1v = m; lo = fminf(x, hi); hi = fmaxf(x, hi); }              \
      t2v = fminf(lo, t2v);                                           \
    }                                                                 \
    thrF = t2v;                                                       \
    cnt = 0; }

  float4 r = pos4[(kbase + 0 * 64 + lane) * 4];
  stg[wv][0][lane] = r;
  r = pos4[(kbase + 1 * 64 + lane) * 4];           // prefetch window 1
  #pragma unroll 1
  for (int w = 0; w < 4; ++w) {
    const float4* wb = stg[wv][w & 1];
    #pragma unroll 1
    for (int g8 = 0; g8 < 64; g8 += 8) {
      #pragma unroll
      for (int u = 0; u < 8; ++u) {
        float d2 = dist2(qp, wb[g8 + u]);          // uniform ds_read broadcast
        sd[cnt * 1024 + tid] = d2;                 // unconditional (slot <= 10)
        cnt += (d2 < thrF) ? 1 : 0;
      }
      if (__any(cnt >= TRIG3)) { FLUSH3(); }
    }
    if (w < 3) {
      stg[wv][(w + 1) & 1][lane] = r;              // vmcnt long satisfied
      if (w < 2) r = pos4[(kbase + (w + 2) * 64 + lane) * 4];
    }
  }
  FLUSH3();

  md[wv][lane][0] = t0v;
  md[wv][lane][1] = t1v;
  md[wv][lane][2] = t2v;
  md[wv][lane][3] = INF;                 // sentinel: heads may clamp at 3
  __syncthreads();

  if (tid < 64) {                        // 16-way merge of top-3 lists, take 20th
    int ql = tid;
    int h0=0,h1=0,h2=0,h3=0,h4=0,h5=0,h6=0,h7=0;
    int h8=0,h9=0,h10=0,h11=0,h12=0,h13=0,h14=0,h15=0;
    float last = INF;
    for (int r2 = 0; r2 < KNNK; ++r2) {  // 48 finite values exist -> last finite
      float c0 = md[ 0][ql][h0],  c1 = md[ 1][ql][h1];
      float c2 = md[ 2][ql][h2],  c3 = md[ 3][ql][h3];
      float c4 = md[ 4][ql][h4],  c5 = md[ 5][ql][h5];
      float c6 = md[ 6][ql][h6],  c7 = md[ 7][ql][h7];
      float c8 = md[ 8][ql][h8],  c9 = md[ 9][ql][h9];
      float cA = md[10][ql][h10], cB = md[11][ql][h11];
      float cC = md[12][ql][h12], cD = md[13][ql][h13];
      float cE = md[14][ql][h14], cF = md[15][ql][h15];
      float bv = c0; int bw = 0;
      if (c1 < bv) { bv = c1; bw = 1; }
      if (c2 < bv) { bv = c2; bw = 2; }
      if (c3 < bv) { bv = c3; bw = 3; }
      if (c4 < bv) { bv = c4; bw = 4; }
      if (c5 < bv) { bv = c5; bw = 5; }
      if (c6 < bv) { bv = c6; bw = 6; }
      if (c7 < bv) { bv = c7; bw = 7; }
      if (c8 < bv) { bv = c8; bw = 8; }
      if (c9 < bv) { bv = c9; bw = 9; }
      if (cA < bv) { bv = cA; bw = 10; }
      if (cB < bv) { bv = cB; bw = 11; }
      if (cC < bv) { bv = cC; bw = 12; }
      if (cD < bv) { bv = cD; bw = 13; }
      if (cE < bv) { bv = cE; bw = 14; }
      if (cF < bv) { bv = cF; bw = 15; }
      last = bv;
      h0  += (bw==0);  h1  += (bw==1);  h2  += (bw==2);  h3  += (bw==3);
      h4  += (bw==4);  h5  += (bw==5);  h6  += (bw==6);  h7  += (bw==7);
      h8  += (bw==8);  h9  += (bw==9);  h10 += (bw==10); h11 += (bw==11);
      h12 += (bw==12); h13 += (bw==13); h14 += (bw==14); h15 += (bw==15);
    }
    tau[qg * 64 + ql] = last * 1.00001f;
  }
}

// ---------------------------------------------------------------- s1x: scalar-broadcast screen, batch-16
// grid 1024 = 256 qg x 4 part-blocks; block 4 waves; wave -> part = pb*4+wv.
// LANE = QUERY; candidates via wave-uniform scalar loads in serial batches of
// 16. Survivors -> private per-(q,part) segment: no atomics, no LDS.
__global__ __launch_bounds__(256) void knnconv_s1x(const float4* __restrict__ pos4,
                                                   const float* __restrict__ tau,
                                                   u16* __restrict__ g1,
                                                   u16* __restrict__ gcnt) {
  const int tid  = threadIdx.x;
  const int lane = tid & 63;
  const int wv   = __builtin_amdgcn_readfirstlane(tid >> 6);   // uniform -> SGPR
  const int qg   = blockIdx.x >> 2;
  const int pb   = blockIdx.x & 3;
  const int part = pb * 4 + wv;          // 0..15, one wave owns one part
  const int q    = qg * 64 + lane;
  const float4 P = pos4[q];
  const float Qx = P.x, Qy = P.y, Qz = P.z;
  const float Qt = 0.5f * (tau[q] - P.w);
  const int cbase = part * PSZ;
  const float4* cp = pos4 + cbase;       // SGPR base -> s_load candidates
  u16* seg = g1 + (q * NSEG + part) * SCAP;
  int cnt = 0;

  #pragma unroll 1
  for (int t0 = 0; t0 < PSZ; t0 += 16) {
    float4 c[16];
    #pragma unroll
    for (int u = 0; u < 16; ++u) c[u] = cp[t0 + u];    // wave-uniform scalar loads
    #pragma unroll
    for (int u = 0; u < 16; ++u) {
      float dot = fmaf(Qx, c[u].x, fmaf(Qy, c[u].y, Qz * c[u].z));
      float lhs = fmaf(0.5f, c[u].w, -dot);            // 0.5*cw - dot
      if (lhs <= Qt) {                                 // rare (p ~ 0.5% per lane)
        if (cnt < SCAP) seg[cnt] = (u16)(cbase + t0 + u);
        ++cnt;
      }
    }
  }
  gcnt[q * NSEG + part] = (u16)min(cnt, SCAP);
}

// ---------------------------------------------------------------- s2: gather + f64 re-rank
// block = 16 queries x 16 segment-threads; keys[16][256] u64; rank-count.
__global__ __launch_bounds__(256) void knnconv_s2(const float4* __restrict__ pos4,
                                                  const u16* __restrict__ g1,
                                                  const u16* __restrict__ gcnt,
                                                  u16* __restrict__ knn_out) {
  __shared__ u64 keys[16 * 256];         // 32KB
  __shared__ int Tq[16];
  const int tid = threadIdx.x;
  const int iq = tid >> 4, s = tid & 15;
  const int q0 = blockIdx.x * 16;
  const int q = q0 + iq;

  #pragma unroll
  for (int i = 0; i < 16; ++i) keys[i * 256 + tid] = ~0ULL;
  __syncthreads();

  int off = 0, T = 0;
  #pragma unroll
  for (int j = 0; j < NSEG; ++j) {
    int cj = gcnt[q * NSEG + j];
    off += (j < s) ? cj : 0;
    T += cj;
  }
  if (s == 15) Tq[iq] = min(T, 256);
  int myc = gcnt[q * NSEG + s];
  float4 P = pos4[q];
  for (int i = 0; i < myc; ++i) {
    int pos = off + i;
    if (pos >= 256) break;               // deterministic clamp (P ~ 0)
    int cidx = (int)g1[(q * NSEG + s) * SCAP + i];
    float4 C = pos4[cidx];
    double qx = P.x, qy = P.y, qz = P.z;
    double cx = C.x, cy = C.y, cz = C.z;
    double sqq = qx * qx + qy * qy + qz * qz;
    double sqc = cx * cx + cy * cy + cz * cz;
    double dot = qx * cx + qy * cy + qz * cz;
    double d   = (sqq + sqc) - 2.0 * dot;              // exact to ~1e-16
    float df = fmaxf((float)d, 0.0f);                  // one rounding, 6e-8 rel
    keys[iq * 256 + pos] = ((u64)__builtin_bit_cast(u32, df) << 14) | (u32)cidx;
  }
  __syncthreads();

  #pragma unroll 1
  for (int t = 0; t < 16; ++t) {         // uniform per-block iteration
    int T2 = Tq[t];
    if (tid < T2) {
      u64 kj = keys[t * 256 + tid];
      const u64* row = keys + t * 256;
      int r = 0;
      for (int k = 0; k < T2; ++k) r += (row[k] < kj) ? 1 : 0;   // broadcast reads
      if (r < KNNK)
        knn_out[(q0 + t) * KNNK + r] = (u16)(kj & 0x3FFFu);
    }
  }
}

// ---------------------------------------------------------------- W1/W2 -> pre-swizzled bf16 (one-shot)
__global__ __launch_bounds__(256) void knnconv_wprep(const float* __restrict__ W1,
                                                     const float* __restrict__ W2,
                                                     u16* __restrict__ w1bf,
                                                     u16* __restrict__ w2bf) {
  int b = blockIdx.x;
  if (b < 128) {
    int e = b * 256 + threadIdx.x;       // 32768 entries
    int n = e >> 7, kk = e & 127;
    float v;
    if (n < 128) v = W1[(128 + kk) * 128 + n];                              // W1d
    else { int n2 = n - 128; v = W1[kk * 128 + n2] - W1[(128 + kk) * 128 + n2]; }  // W1c-W1d
    w1bf[(n * 256 + ((kk * 2) ^ ((n & 7) << 4))) >> 1] = f2bf(v);
  } else {
    int e = (b - 128) * 256 + threadIdx.x;   // 16384 entries
    int n = e >> 7, kk = e & 127;
    w2bf[(n * 256 + ((kk * 2) ^ ((n & 7) << 4))) >> 1] = f2bf(W2[kk * 128 + n]);
  }
}

// ---------------------------------------------------------------- precompute a = f@W1d (bf16), c = f@(W1c-W1d)+b1 (f32)
__global__ __launch_bounds__(256) void knnconv_prec(const float* __restrict__ feat,
                                                    const u16* __restrict__ w1bf,
                                                    const float* __restrict__ b1,
                                                    u16* __restrict__ a_out,
                                                    float* __restrict__ c_out) {
  __shared__ char sW[65536];   // WT[n=256][k=128] bf16, pre-swizzled (linear copy)
  __shared__ char sF[16384];   // FA[m=64][k=128] bf16, XOR-swizzled
  const int tid = threadIdx.x;
  { // linear coalesced copy of pre-swizzled W1-combined
    const uint4* src = (const uint4*)w1bf;
    uint4* dst = (uint4*)sW;
    #pragma unroll
    for (int r = 0; r < 16; ++r) dst[r * 256 + tid] = src[r * 256 + tid];
  }
  { // stage FA rows (bf16x8 per lane)
    int sub = tid & 15, r0 = tid >> 4;
    int m0 = blockIdx.x * 64;
    for (int rr = 0; rr < 4; ++rr) {
      int r = r0 + rr * 16;
      const float* src = feat + (m0 + r) * 128 + sub * 8;
      float4 v0 = *(const float4*)src;
      float4 v1 = *(const float4*)(src + 4);
      u32 p0 = (u32)f2bf(v0.x) | ((u32)f2bf(v0.y) << 16);
      u32 p1 = (u32)f2bf(v0.z) | ((u32)f2bf(v0.w) << 16);
      u32 p2 = (u32)f2bf(v1.x) | ((u32)f2bf(v1.y) << 16);
      u32 p3 = (u32)f2bf(v1.z) | ((u32)f2bf(v1.w) << 16);
      *(uint4*)(sF + r * 256 + ((sub * 16) ^ ((r & 7) << 4))) = make_uint4(p0, p1, p2, p3);
    }
  }
  __syncthreads();
  const int lane = tid & 63, wv = tid >> 6;
  const int l15 = lane & 15, l4 = lane >> 4;
  f32x4 acc[4][4];
  #pragma unroll
  for (int a = 0; a < 4; ++a)
    #pragma unroll
    for (int b = 0; b < 4; ++b) acc[a][b] = (f32x4){0.f, 0.f, 0.f, 0.f};
  #pragma unroll
  for (int kk = 0; kk < 4; ++kk) {
    int kb = kk * 64 + l4 * 16;
    s16x8 af[4], bfr[4];
    #pragma unroll
    for (int mt = 0; mt < 4; ++mt) {
      int row = mt * 16 + l15;
      af[mt] = *(const s16x8*)(sF + row * 256 + (kb ^ ((row & 7) << 4)));
    }
    #pragma unroll
    for (int nt = 0; nt < 4; ++nt) {
      int n = (wv * 4 + nt) * 16 + l15;
      bfr[nt] = *(const s16x8*)(sW + n * 256 + (kb ^ ((n & 7) << 4)));
    }
    #pragma unroll
    for (int mt = 0; mt < 4; ++mt)
      #pragma unroll
      for (int nt = 0; nt < 4; ++nt)
        acc[mt][nt] = MFMA_BF16(af[mt], bfr[nt], acc[mt][nt], 0, 0, 0);
  }
  int m0 = blockIdx.x * 64;
  #pragma unroll
  for (int nt = 0; nt < 4; ++nt) {
    int n = (wv * 4 + nt) * 16 + l15;
    float bias = (n >= 128) ? b1[n - 128] : 0.0f;
    #pragma unroll
    for (int mt = 0; mt < 4; ++mt)
      #pragma unroll
      for (int r = 0; r < 4; ++r) {
        int m = m0 + mt * 16 + l4 * 4 + r;    // C/D: row=(l>>4)*4+reg, col=l&15
        float v = acc[mt][nt][r];
        if (n < 128) a_out[m * 128 + n] = f2bf(v);
        else         c_out[m * 128 + (n - 128)] = v + bias;
      }
  }
}

// ---------------------------------------------------------------- fused gather + relu + GEMM2 + max
// block = 8 queries (160 rows), 4 waves x 2 n-tiles. Changes vs R21:
//  (a) W2 B-frags loaded DIRECTLY from pre-swizzled global w2bf into registers
//      (8 x 16B L2 gathers) -- no 32KB LDS copy; LDS 77824 -> 45056 B
//      => 3 blocks/CU (was 2), +50% waves.
//  (b) Group-max epilogue: acc[mt][nt] covers rows [4g,4g+4), g=mt*4+l4;
//      query qq rows [20qq,20qq+20) = groups [5qq,5qq+5). Write one f32 group
//      max to sG[40][129] (padded: conflict-free), final max reads 5 groups.
//      Same f32 values, max assoc/comm -> bit-identical output.
__global__ __launch_bounds__(256) void knnconv_conv(const u16* __restrict__ knn,
                                                    const u16* __restrict__ a_in,
                                                    const float* __restrict__ c_in,
                                                    const u16* __restrict__ w2bf,
                                                    const float* __restrict__ b2,
                                                    float* __restrict__ out) {
  __shared__ char lds[45056];     // [0,40960): A (bf16 swz) -> sG[40][129] f32 | [40960,45056): c rows
  char* sA = lds;
  float* sG = (float*)lds;
  char* sC = lds + 40960;
  const int tid = threadIdx.x;
  const int q0 = blockIdx.x * 8;
  const int lane = tid & 63, wv = tid >> 6;
  const int l15 = lane & 15, l4 = lane >> 4;

  // B-fragments straight from global (w2bf layout == the swizzled LDS layout)
  s16x8 bfr[4][2];
  #pragma unroll
  for (int kk = 0; kk < 4; ++kk)
    #pragma unroll
    for (int nt = 0; nt < 2; ++nt) {
      int n = (wv * 2 + nt) * 16 + l15;
      int kb = kk * 64 + l4 * 16;
      bfr[kk][nt] = *(const s16x8*)((const char*)w2bf + n * 256 + (kb ^ ((n & 7) << 4)));
    }

  { // stage c rows for the 8 queries
    int row = tid >> 5, ch4 = (tid & 31) * 4;
    *(float4*)(sC + (row * 128 + ch4) * 4) = *(const float4*)(c_in + (q0 + row) * 128 + ch4);
  }
  __syncthreads();
  { // stage A: row r = (query il, neighbor ke): relu(a[idx] + c[il]) -> bf16, swizzled
    int sub = tid & 15, rr = tid >> 4;
    for (int p = 0; p < 10; ++p) {
      int r = p * 16 + rr;
      int il = r / 20;
      int ke = r - il * 20;
      int idx = (int)knn[(q0 + il) * KNNK + ke];
      uint4 av = *(const uint4*)(a_in + idx * 128 + sub * 8);
      float4 c0 = *(const float4*)(sC + (il * 128 + sub * 8) * 4);
      float4 c1 = *(const float4*)(sC + (il * 128 + sub * 8 + 4) * 4);
      float h0 = fmaxf(bf2f((u16)(av.x & 0xFFFF)) + c0.x, 0.f);
      float h1 = fmaxf(bf2f((u16)(av.x >> 16))    + c0.y, 0.f);
      float h2 = fmaxf(bf2f((u16)(av.y & 0xFFFF)) + c0.z, 0.f);
      float h3 = fmaxf(bf2f((u16)(av.y >> 16))    + c0.w, 0.f);
      float h4 = fmaxf(bf2f((u16)(av.z & 0xFFFF)) + c1.x, 0.f);
      float h5 = fmaxf(bf2f((u16)(av.z >> 16))    + c1.y, 0.f);
      float h6 = fmaxf(bf2f((u16)(av.w & 0xFFFF)) + c1.z, 0.f);
      float h7 = fmaxf(bf2f((u16)(av.w >> 16))    + c1.w, 0.f);
      u32 p0 = (u32)f2bf(h0) | ((u32)f2bf(h1) << 16);
      u32 p1 = (u32)f2bf(h2) | ((u32)f2bf(h3) << 16);
      u32 p2 = (u32)f2bf(h4) | ((u32)f2bf(h5) << 16);
      u32 p3 = (u32)f2bf(h6) | ((u32)f2bf(h7) << 16);
      *(uint4*)(sA + r * 256 + ((sub * 16) ^ ((r & 7) << 4))) = make_uint4(p0, p1, p2, p3);
    }
  }
  __syncthreads();
  f32x4 acc[10][2];
  #pragma unroll
  for (int mt = 0; mt < 10; ++mt) { acc[mt][0] = (f32x4){0,0,0,0}; acc[mt][1] = (f32x4){0,0,0,0}; }
  #pragma unroll
  for (int kk = 0; kk < 4; ++kk) {
    int kb = kk * 64 + l4 * 16;
    #pragma unroll
    for (int mt = 0; mt < 10; ++mt) {
      int row = mt * 16 + l15;
      s16x8 a = *(const s16x8*)(sA + row * 256 + (kb ^ ((row & 7) << 4)));
      acc[mt][0] = MFMA_BF16(a, bfr[kk][0], acc[mt][0], 0, 0, 0);
      acc[mt][1] = MFMA_BF16(a, bfr[kk][1], acc[mt][1], 0, 0, 0);
    }
  }
  __syncthreads();              // all waves done reading A before sG overwrite
  #pragma unroll
  for (int mt = 0; mt < 10; ++mt) {
    int g = mt * 4 + l4;        // 4-row group index, rows [4g, 4g+4)
    #pragma unroll
    for (int nt = 0; nt < 2; ++nt) {
      int col = (wv * 2 + nt) * 16 + l15;
      f32x4 a4 = acc[mt][nt];
      float gm = fmaxf(fmaxf(a4[0], a4[1]), fmaxf(a4[2], a4[3]));
      sG[g * 129 + col] = gm;   // padded stride: conflict-free across l4
    }
  }
  __syncthreads();
  { // final max over 5 groups + b2; 4 output elems per thread
    #pragma unroll
    for (int e = 0; e < 4; ++e) {
      int elem = e * 256 + tid;           // 1024 = 8q x 128ch
      int qq = elem >> 7, ch = elem & 127;
      const float* gp = sG + (qq * 5) * 129 + ch;
      float mx = gp[0];
      mx = fmaxf(mx, gp[129]);
      mx = fmaxf(mx, gp[258]);
      mx = fmaxf(mx, gp[387]);
      mx = fmaxf(mx, gp[516]);
      out[(q0 + qq) * 128 + ch] = mx + b2[ch];
    }
  }
}

// ---------------------------------------------------------------- launch
extern "C" void kernel_launch(void* const* d_in, const int* in_sizes, int n_in,
                              void* d_out, int out_size, void* d_ws, size_t ws_size,
                              hipStream_t stream) {
  const float* pos  = (const float*)d_in[0];
  const float* feat = (const float*)d_in[1];
  const float* W1   = (const float*)d_in[2];
  const float* b1   = (const float*)d_in[3];
  const float* W2   = (const float*)d_in[4];
  const float* b2   = (const float*)d_in[5];
  float* out = (float*)d_out;
  char* ws = (char*)d_ws;
  // ws layout (aliases noted):
  //  [0,256K)              pos4 (prep..s2)        -> w1bf 64KB + w2bf 32KB (wprep..conv)
  //  [256K,917504)         knn u16 (s2..conv)
  //  [917504,13500416)     g1 [16384][16][24] u16 (s1x..s2) -> a_buf 4MB + c_buf 8MB (prec..conv)
  //  [13500416,14024704)   gcnt [16384][16] u16 (s1x..s2)
  //  [14024704,14090240)   tau [16384] f32 (s0..s1x)
  float4* pos4  = (float4*)ws;
  u16*    w1bf  = (u16*)ws;
  u16*    w2bf  = (u16*)(ws + 65536);
  u16*    knn   = (u16*)(ws + 262144);
  u16*    g1    = (u16*)(ws + 917504);
  u16*    a_buf = (u16*)(ws + 917504);
  float*  c_buf = (float*)(ws + 5111808);
  u16*    gcnt  = (u16*)(ws + 13500416);
  float*  tau   = (float*)(ws + 14024704);
  if (ws_size < 14090240) return;   // insufficient scratch (would corrupt)

  knnconv_prep<<<64, 256, 0, stream>>>(pos, pos4);
  knnconv_s0<<<256, 1024, 0, stream>>>(pos4, tau);
  knnconv_s1x<<<1024, 256, 0, stream>>>(pos4, tau, g1, gcnt);
  knnconv_s2<<<1024, 256, 0, stream>>>(pos4, g1, gcnt, knn);
  knnconv_wprep<<<192, 256, 0, stream>>>(W1, W2, w1bf, w2bf);          // overwrites pos4 (dead)
  knnconv_prec<<<256, 256, 0, stream>>>(feat, w1bf, b1, a_buf, c_buf); // overwrites g1 (dead)
  knnconv_conv<<<2048, 256, 0, stream>>>(knn, a_buf, c_buf, w2bf, b2, out);
}

// Round 23
// 193.202 us; speedup vs baseline: 1.3089x; 1.0151x over previous
//
#include <hip/hip_runtime.h>

typedef unsigned char  u8;
typedef unsigned short u16;
typedef unsigned int   u32;
typedef unsigned long long u64;
typedef short s16x8 __attribute__((ext_vector_type(8)));   // 8 x bf16 bits (4 VGPRs)
typedef float f32x4 __attribute__((ext_vector_type(4)));   // MFMA accumulator

#define NPTS   16384
#define KNNK   20
#define SLOTS3 12      // s0 stack slots (trigger 4, growth <= 8 => max 11)
#define TRIG3  4
#define NSEG   16      // s1x candidate parts per query
#define PSZ    1024    // candidates per part
#define HSZ    512     // candidates per half-part (one wave each)
#define SCAP   24      // survivor cap per (query, part), shared by both halves

#define MFMA_BF16 __builtin_amdgcn_mfma_f32_16x16x32_bf16

__device__ __forceinline__ u16 f2bf(float x) {
  u32 u = __builtin_bit_cast(u32, x);
  u32 r = (u + 0x7FFFu + ((u >> 16) & 1u)) >> 16;   // RNE
  return (u16)r;
}
__device__ __forceinline__ float bf2f(u16 b) {
  u32 u = ((u32)b) << 16;
  return __builtin_bit_cast(float, u);
}
__device__ __forceinline__ float dist2(float4 qp, float4 cd) {
  float dot = fmaf(qp.x, cd.x, fmaf(qp.y, cd.y, qp.z * cd.z));
  return fmaf(-2.0f, dot, qp.w + cd.w);
}

// ---------------------------------------------------------------- prep: pos4 = (x,y,z,|p|^2)
__global__ __launch_bounds__(256) void knnconv_prep(const float* __restrict__ pos,
                                                    float4* __restrict__ pos4) {
  int i = blockIdx.x * 256 + threadIdx.x;
  float x = pos[i * 3 + 0], y = pos[i * 3 + 1], z = pos[i * 3 + 2];
  float sq = (x * x + y * y) + z * z;    // f32 screen only; f64 re-rank decides final set
  pos4[i] = make_float4(x, y, z, sq);
}

// ---------------------------------------------------------------- s0: sample threshold
// grid 256; block 1024 = 16 waves; lane = query. Wave wv scans 256 samples
// (every 4th point) in 4 windows of 64 (intra-wave LDS staging, no barriers).
// Top-3 lazy stack + 16-way merge -> tau = 20th of 48-value union (provable
// superset bound: >=20 full points within tau).
__global__ __launch_bounds__(1024) void knnconv_s0(const float4* __restrict__ pos4,
                                                   float* __restrict__ tau) {
  __shared__ float sd[SLOTS3 * 1024];    // 48KB per-lane stacks
  __shared__ float md[16][64][4];        // 16KB sorted top-3 + INF sentinel
  __shared__ float4 stg[16][2][64];      // 32KB wave-private staging
  const int tid  = threadIdx.x;
  const int lane = tid & 63;
  const int wv   = tid >> 6;             // 0..15
  const int qg   = blockIdx.x;
  const int q    = qg * 64 + lane;
  const float4 qp = pos4[q];
  const float INF = __builtin_inff();

  float t0v = INF, t1v = INF, t2v = INF; // sorted top-3 in registers
  float thrF = INF;
  int cnt = 0;
  const int kbase = wv * 256;            // sample index base (sample i -> point 4i)

#define FLUSH3()                                                      \
  { _Pragma("unroll 1")                                               \
    for (int e = 0; e < SLOTS3; e += 2) {                             \
      if (!__any(e < cnt)) break;                                     \
      float lo = (e     < cnt) ? sd[e * 1024 + tid]       : INF;      \
      float hi = (e + 1 < cnt) ? sd[(e + 1) * 1024 + tid] : INF;      \
      float a_ = fminf(lo, hi), b_ = fmaxf(lo, hi);                   \
      lo = a_; hi = b_;                                               \
      { float m = fminf(lo, t0v), x = fmaxf(lo, t0v);                 \
        t0v = m; lo = fminf(x, hi); hi = fmaxf(x, hi); }              \
      { float m = fminf(lo, t1v), x = fmaxf(lo, t1v);                 \
        t1v = m; lo = fminf(x, hi); hi = fmaxf(x, hi); }              \
      t2v = fminf(lo, t2v);                                           \
    }                                                                 \
    thrF = t2v;                                                       \
    cnt = 0; }

  float4 r = pos4[(kbase + 0 * 64 + lane) * 4];
  stg[wv][0][lane] = r;
  r = pos4[(kbase + 1 * 64 + lane) * 4];           // prefetch window 1
  #pragma unroll 1
  for (int w = 0; w < 4; ++w) {
    const float4* wb = stg[wv][w & 1];
    #pragma unroll 1
    for (int g8 = 0; g8 < 64; g8 += 8) {
      #pragma unroll
      for (int u = 0; u < 8; ++u) {
        float d2 = dist2(qp, wb[g8 + u]);          // uniform ds_read broadcast
        sd[cnt * 1024 + tid] = d2;                 // unconditional (slot <= 10)
        cnt += (d2 < thrF) ? 1 : 0;
      }
      if (__any(cnt >= TRIG3)) { FLUSH3(); }
    }
    if (w < 3) {
      stg[wv][(w + 1) & 1][lane] = r;              // vmcnt long satisfied
      if (w < 2) r = pos4[(kbase + (w + 2) * 64 + lane) * 4];
    }
  }
  FLUSH3();

  md[wv][lane][0] = t0v;
  md[wv][lane][1] = t1v;
  md[wv][lane][2] = t2v;
  md[wv][lane][3] = INF;                 // sentinel: heads may clamp at 3
  __syncthreads();

  if (tid < 64) {                        // 16-way merge of top-3 lists, take 20th
    int ql = tid;
    int h0=0,h1=0,h2=0,h3=0,h4=0,h5=0,h6=0,h7=0;
    int h8=0,h9=0,h10=0,h11=0,h12=0,h13=0,h14=0,h15=0;
    float last = INF;
    for (int r2 = 0; r2 < KNNK; ++r2) {  // 48 finite values exist -> last finite
      float c0 = md[ 0][ql][h0],  c1 = md[ 1][ql][h1];
      float c2 = md[ 2][ql][h2],  c3 = md[ 3][ql][h3];
      float c4 = md[ 4][ql][h4],  c5 = md[ 5][ql][h5];
      float c6 = md[ 6][ql][h6],  c7 = md[ 7][ql][h7];
      float c8 = md[ 8][ql][h8],  c9 = md[ 9][ql][h9];
      float cA = md[10][ql][h10], cB = md[11][ql][h11];
      float cC = md[12][ql][h12], cD = md[13][ql][h13];
      float cE = md[14][ql][h14], cF = md[15][ql][h15];
      float bv = c0; int bw = 0;
      if (c1 < bv) { bv = c1; bw = 1; }
      if (c2 < bv) { bv = c2; bw = 2; }
      if (c3 < bv) { bv = c3; bw = 3; }
      if (c4 < bv) { bv = c4; bw = 4; }
      if (c5 < bv) { bv = c5; bw = 5; }
      if (c6 < bv) { bv = c6; bw = 6; }
      if (c7 < bv) { bv = c7; bw = 7; }
      if (c8 < bv) { bv = c8; bw = 8; }
      if (c9 < bv) { bv = c9; bw = 9; }
      if (cA < bv) { bv = cA; bw = 10; }
      if (cB < bv) { bv = cB; bw = 11; }
      if (cC < bv) { bv = cC; bw = 12; }
      if (cD < bv) { bv = cD; bw = 13; }
      if (cE < bv) { bv = cE; bw = 14; }
      if (cF < bv) { bv = cF; bw = 15; }
      last = bv;
      h0  += (bw==0);  h1  += (bw==1);  h2  += (bw==2);  h3  += (bw==3);
      h4  += (bw==4);  h5  += (bw==5);  h6  += (bw==6);  h7  += (bw==7);
      h8  += (bw==8);  h9  += (bw==9);  h10 += (bw==10); h11 += (bw==11);
      h12 += (bw==12); h13 += (bw==13); h14 += (bw==14); h15 += (bw==15);
    }
    tau[qg * 64 + ql] = last * 1.00001f;
  }
}

// ---------------------------------------------------------------- s1x: scalar-broadcast screen, half-parts
// grid 2048 = 256 qg x 8 pb (pb&3 -> part group, pb>>2 -> half); block 4 waves;
// wave -> part = (pb&3)*4+wv, scans candidates [part*1024 + half*512, +512).
// 8 blocks/CU => 8 waves/SIMD (2x R22) to hide the SMEM drain latency.
// BIDIRECTIONAL APPEND: half 0 writes segment slots 0.. ascending, half 1
// writes SCAP-1.. descending; collision iff cntA+cntB > SCAP (same total
// distribution as the proven SCAP=24 cap, P~1e-4; s2 clamps deterministically).
// s2's rank-sort is order-invariant -> output identical.
__global__ __launch_bounds__(256) void knnconv_s1x(const float4* __restrict__ pos4,
                                                   const float* __restrict__ tau,
                                                   u16* __restrict__ g1,
                                                   u8* __restrict__ gcnt8) {
  const int tid  = threadIdx.x;
  const int lane = tid & 63;
  const int wv   = __builtin_amdgcn_readfirstlane(tid >> 6);   // uniform -> SGPR
  const int qg   = blockIdx.x >> 3;
  const int pb   = blockIdx.x & 7;
  const int part = (pb & 3) * 4 + wv;    // 0..15
  const int half = pb >> 2;              // 0..1
  const int q    = qg * 64 + lane;
  const float4 P = pos4[q];
  const float Qx = P.x, Qy = P.y, Qz = P.z;
  const float Qt = 0.5f * (tau[q] - P.w);
  const int cbase = part * PSZ + half * HSZ;
  const float4* cp = pos4 + cbase;       // SGPR base -> s_load candidates
  u16* seg = g1 + (q * NSEG + part) * SCAP;
  int cnt = 0;

  #pragma unroll 1
  for (int t0 = 0; t0 < HSZ; t0 += 16) {
    float4 c[16];
    #pragma unroll
    for (int u = 0; u < 16; ++u) c[u] = cp[t0 + u];    // wave-uniform scalar loads
    #pragma unroll
    for (int u = 0; u < 16; ++u) {
      float dot = fmaf(Qx, c[u].x, fmaf(Qy, c[u].y, Qz * c[u].z));
      float lhs = fmaf(0.5f, c[u].w, -dot);            // 0.5*cw - dot
      if (lhs <= Qt) {                                 // rare (p ~ 0.5% per lane)
        if (cnt < SCAP) {
          int slot = half ? (SCAP - 1 - cnt) : cnt;
          seg[slot] = (u16)(cbase + t0 + u);
        }
        ++cnt;
      }
    }
  }
  gcnt8[(q * NSEG + part) * 2 + half] = (u8)min(cnt, SCAP);
}

// ---------------------------------------------------------------- s2: gather + f64 re-rank
// block = 16 queries x 16 segment-threads; each thread gathers BOTH halves of
// its segment (ascending block + descending block); keys[16][256]; rank-count.
__global__ __launch_bounds__(256) void knnconv_s2(const float4* __restrict__ pos4,
                                                  const u16* __restrict__ g1,
                                                  const u8* __restrict__ gcnt8,
                                                  u16* __restrict__ knn_out) {
  __shared__ u64 keys[16 * 256];         // 32KB
  __shared__ int Tq[16];
  const int tid = threadIdx.x;
  const int iq = tid >> 4, s = tid & 15;
  const int q0 = blockIdx.x * 16;
  const int q = q0 + iq;

  #pragma unroll
  for (int i = 0; i < 16; ++i) keys[i * 256 + tid] = ~0ULL;
  __syncthreads();

  int off = 0, T = 0, myA = 0, myB = 0;
  #pragma unroll
  for (int j = 0; j < NSEG; ++j) {
    int a = (int)gcnt8[(q * NSEG + j) * 2 + 0];
    int b = (int)gcnt8[(q * NSEG + j) * 2 + 1];
    b = min(b, SCAP - a);                // deterministic clamp (collision P~1e-4)
    int tj = a + b;
    off += (j < s) ? tj : 0;
    T += tj;
    if (j == s) { myA = a; myB = b; }
  }
  if (s == 15) Tq[iq] = min(T, 256);
  const u16* segp = g1 + (q * NSEG + s) * SCAP;
  float4 P = pos4[q];
  #pragma unroll 1
  for (int i = 0; i < myA + myB; ++i) {
    int pos = off + i;
    if (pos >= 256) break;               // deterministic clamp (P ~ 0)
    int cidx = (int)((i < myA) ? segp[i] : segp[SCAP - 1 - (i - myA)]);
    float4 C = pos4[cidx];
    double qx = P.x, qy = P.y, qz = P.z;
    double cx = C.x, cy = C.y, cz = C.z;
    double sqq = qx * qx + qy * qy + qz * qz;
    double sqc = cx * cx + cy * cy + cz * cz;
    double dot = qx * cx + qy * cy + qz * cz;
    double d   = (sqq + sqc) - 2.0 * dot;              // exact to ~1e-16
    float df = fmaxf((float)d, 0.0f);                  // one rounding, 6e-8 rel
    keys[iq * 256 + pos] = ((u64)__builtin_bit_cast(u32, df) << 14) | (u32)cidx;
  }
  __syncthreads();

  #pragma unroll 1
  for (int t = 0; t < 16; ++t) {         // uniform per-block iteration
    int T2 = Tq[t];
    if (tid < T2) {
      u64 kj = keys[t * 256 + tid];
      const u64* row = keys + t * 256;
      int r = 0;
      for (int k = 0; k < T2; ++k) r += (row[k] < kj) ? 1 : 0;   // broadcast reads
      if (r < KNNK)
        knn_out[(q0 + t) * KNNK + r] = (u16)(kj & 0x3FFFu);
    }
  }
}

// ---------------------------------------------------------------- W1/W2 -> pre-swizzled bf16 (one-shot)
__global__ __launch_bounds__(256) void knnconv_wprep(const float* __restrict__ W1,
                                                     const float* __restrict__ W2,
                                                     u16* __restrict__ w1bf,
                                                     u16* __restrict__ w2bf) {
  int b = blockIdx.x;
  if (b < 128) {
    int e = b * 256 + threadIdx.x;       // 32768 entries
    int n = e >> 7, kk = e & 127;
    float v;
    if (n < 128) v = W1[(128 + kk) * 128 + n];                              // W1d
    else { int n2 = n - 128; v = W1[kk * 128 + n2] - W1[(128 + kk) * 128 + n2]; }  // W1c-W1d
    w1bf[(n * 256 + ((kk * 2) ^ ((n & 7) << 4))) >> 1] = f2bf(v);
  } else {
    int e = (b - 128) * 256 + threadIdx.x;   // 16384 entries
    int n = e >> 7, kk = e & 127;
    w2bf[(n * 256 + ((kk * 2) ^ ((n & 7) << 4))) >> 1] = f2bf(W2[kk * 128 + n]);
  }
}

// ---------------------------------------------------------------- precompute a = f@W1d (bf16), c = f@(W1c-W1d)+b1 (f32)
__global__ __launch_bounds__(256) void knnconv_prec(const float* __restrict__ feat,
                                                    const u16* __restrict__ w1bf,
                                                    const float* __restrict__ b1,
                                                    u16* __restrict__ a_out,
                                                    float* __restrict__ c_out) {
  __shared__ char sW[65536];   // WT[n=256][k=128] bf16, pre-swizzled (linear copy)
  __shared__ char sF[16384];   // FA[m=64][k=128] bf16, XOR-swizzled
  const int tid = threadIdx.x;
  { // linear coalesced copy of pre-swizzled W1-combined
    const uint4* src = (const uint4*)w1bf;
    uint4* dst = (uint4*)sW;
    #pragma unroll
    for (int r = 0; r < 16; ++r) dst[r * 256 + tid] = src[r * 256 + tid];
  }
  { // stage FA rows (bf16x8 per lane)
    int sub = tid & 15, r0 = tid >> 4;
    int m0 = blockIdx.x * 64;
    for (int rr = 0; rr < 4; ++rr) {
      int r = r0 + rr * 16;
      const float* src = feat + (m0 + r) * 128 + sub * 8;
      float4 v0 = *(const float4*)src;
      float4 v1 = *(const float4*)(src + 4);
      u32 p0 = (u32)f2bf(v0.x) | ((u32)f2bf(v0.y) << 16);
      u32 p1 = (u32)f2bf(v0.z) | ((u32)f2bf(v0.w) << 16);
      u32 p2 = (u32)f2bf(v1.x) | ((u32)f2bf(v1.y) << 16);
      u32 p3 = (u32)f2bf(v1.z) | ((u32)f2bf(v1.w) << 16);
      *(uint4*)(sF + r * 256 + ((sub * 16) ^ ((r & 7) << 4))) = make_uint4(p0, p1, p2, p3);
    }
  }
  __syncthreads();
  const int lane = tid & 63, wv = tid >> 6;
  const int l15 = lane & 15, l4 = lane >> 4;
  f32x4 acc[4][4];
  #pragma unroll
  for (int a = 0; a < 4; ++a)
    #pragma unroll
    for (int b = 0; b < 4; ++b) acc[a][b] = (f32x4){0.f, 0.f, 0.f, 0.f};
  #pragma unroll
  for (int kk = 0; kk < 4; ++kk) {
    int kb = kk * 64 + l4 * 16;
    s16x8 af[4], bfr[4];
    #pragma unroll
    for (int mt = 0; mt < 4; ++mt) {
      int row = mt * 16 + l15;
      af[mt] = *(const s16x8*)(sF + row * 256 + (kb ^ ((row & 7) << 4)));
    }
    #pragma unroll
    for (int nt = 0; nt < 4; ++nt) {
      int n = (wv * 4 + nt) * 16 + l15;
      bfr[nt] = *(const s16x8*)(sW + n * 256 + (kb ^ ((n & 7) << 4)));
    }
    #pragma unroll
    for (int mt = 0; mt < 4; ++mt)
      #pragma unroll
      for (int nt = 0; nt < 4; ++nt)
        acc[mt][nt] = MFMA_BF16(af[mt], bfr[nt], acc[mt][nt], 0, 0, 0);
  }
  int m0 = blockIdx.x * 64;
  #pragma unroll
  for (int nt = 0; nt < 4; ++nt) {
    int n = (wv * 4 + nt) * 16 + l15;
    float bias = (n >= 128) ? b1[n - 128] : 0.0f;
    #pragma unroll
    for (int mt = 0; mt < 4; ++mt)
      #pragma unroll
      for (int r = 0; r < 4; ++r) {
        int m = m0 + mt * 16 + l4 * 4 + r;    // C/D: row=(l>>4)*4+reg, col=l&15
        float v = acc[mt][nt][r];
        if (n < 128) a_out[m * 128 + n] = f2bf(v);
        else         c_out[m * 128 + (n - 128)] = v + bias;
      }
  }
}

// ---------------------------------------------------------------- fused gather + relu + GEMM2 + max
// block = 8 queries (160 rows), 4 waves x 2 n-tiles. W2 B-frags direct from
// pre-swizzled global; LDS 45056 -> 3 blocks/CU; f32 group-max epilogue.
__global__ __launch_bounds__(256) void knnconv_conv(const u16* __restrict__ knn,
                                                    const u16* __restrict__ a_in,
                                                    const float* __restrict__ c_in,
                                                    const u16* __restrict__ w2bf,
                                                    const float* __restrict__ b2,
                                                    float* __restrict__ out) {
  __shared__ char lds[45056];     // [0,40960): A (bf16 swz) -> sG[40][129] f32 | [40960,45056): c rows
  char* sA = lds;
  float* sG = (float*)lds;
  char* sC = lds + 40960;
  const int tid = threadIdx.x;
  const int q0 = blockIdx.x * 8;
  const int lane = tid & 63, wv = tid >> 6;
  const int l15 = lane & 15, l4 = lane >> 4;

  // B-fragments straight from global (w2bf layout == the swizzled LDS layout)
  s16x8 bfr[4][2];
  #pragma unroll
  for (int kk = 0; kk < 4; ++kk)
    #pragma unroll
    for (int nt = 0; nt < 2; ++nt) {
      int n = (wv * 2 + nt) * 16 + l15;
      int kb = kk * 64 + l4 * 16;
      bfr[kk][nt] = *(const s16x8*)((const char*)w2bf + n * 256 + (kb ^ ((n & 7) << 4)));
    }

  { // stage c rows for the 8 queries
    int row = tid >> 5, ch4 = (tid & 31) * 4;
    *(float4*)(sC + (row * 128 + ch4) * 4) = *(const float4*)(c_in + (q0 + row) * 128 + ch4);
  }
  __syncthreads();
  { // stage A: row r = (query il, neighbor ke): relu(a[idx] + c[il]) -> bf16, swizzled
    int sub = tid & 15, rr = tid >> 4;
    for (int p = 0; p < 10; ++p) {
      int r = p * 16 + rr;
      int il = r / 20;
      int ke = r - il * 20;
      int idx = (int)knn[(q0 + il) * KNNK + ke];
      uint4 av = *(const uint4*)(a_in + idx * 128 + sub * 8);
      float4 c0 = *(const float4*)(sC + (il * 128 + sub * 8) * 4);
      float4 c1 = *(const float4*)(sC + (il * 128 + sub * 8 + 4) * 4);
      float h0 = fmaxf(bf2f((u16)(av.x & 0xFFFF)) + c0.x, 0.f);
      float h1 = fmaxf(bf2f((u16)(av.x >> 16))    + c0.y, 0.f);
      float h2 = fmaxf(bf2f((u16)(av.y & 0xFFFF)) + c0.z, 0.f);
      float h3 = fmaxf(bf2f((u16)(av.y >> 16))    + c0.w, 0.f);
      float h4 = fmaxf(bf2f((u16)(av.z & 0xFFFF)) + c1.x, 0.f);
      float h5 = fmaxf(bf2f((u16)(av.z >> 16))    + c1.y, 0.f);
      float h6 = fmaxf(bf2f((u16)(av.w & 0xFFFF)) + c1.z, 0.f);
      float h7 = fmaxf(bf2f((u16)(av.w >> 16))    + c1.w, 0.f);
      u32 p0 = (u32)f2bf(h0) | ((u32)f2bf(h1) << 16);
      u32 p1 = (u32)f2bf(h2) | ((u32)f2bf(h3) << 16);
      u32 p2 = (u32)f2bf(h4) | ((u32)f2bf(h5) << 16);
      u32 p3 = (u32)f2bf(h6) | ((u32)f2bf(h7) << 16);
      *(uint4*)(sA + r * 256 + ((sub * 16) ^ ((r & 7) << 4))) = make_uint4(p0, p1, p2, p3);
    }
  }
  __syncthreads();
  f32x4 acc[10][2];
  #pragma unroll
  for (int mt = 0; mt < 10; ++mt) { acc[mt][0] = (f32x4){0,0,0,0}; acc[mt][1] = (f32x4){0,0,0,0}; }
  #pragma unroll
  for (int kk = 0; kk < 4; ++kk) {
    int kb = kk * 64 + l4 * 16;
    #pragma unroll
    for (int mt = 0; mt < 10; ++mt) {
      int row = mt * 16 + l15;
      s16x8 a = *(const s16x8*)(sA + row * 256 + (kb ^ ((row & 7) << 4)));
      acc[mt][0] = MFMA_BF16(a, bfr[kk][0], acc[mt][0], 0, 0, 0);
      acc[mt][1] = MFMA_BF16(a, bfr[kk][1], acc[mt][1], 0, 0, 0);
    }
  }
  __syncthreads();              // all waves done reading A before sG overwrite
  #pragma unroll
  for (int mt = 0; mt < 10; ++mt) {
    int g = mt * 4 + l4;        // 4-row group index, rows [4g, 4g+4)
    #pragma unroll
    for (int nt = 0; nt < 2; ++nt) {
      int col = (wv * 2 + nt) * 16 + l15;
      f32x4 a4 = acc[mt][nt];
      float gm = fmaxf(fmaxf(a4[0], a4[1]), fmaxf(a4[2], a4[3]));
      sG[g * 129 + col] = gm;   // padded stride: conflict-free across l4
    }
  }
  __syncthreads();
  { // final max over 5 groups + b2; 4 output elems per thread
    #pragma unroll
    for (int e = 0; e < 4; ++e) {
      int elem = e * 256 + tid;           // 1024 = 8q x 128ch
      int qq = elem >> 7, ch = elem & 127;
      const float* gp = sG + (qq * 5) * 129 + ch;
      float mx = gp[0];
      mx = fmaxf(mx, gp[129]);
      mx = fmaxf(mx, gp[258]);
      mx = fmaxf(mx, gp[387]);
      mx = fmaxf(mx, gp[516]);
      out[(q0 + qq) * 128 + ch] = mx + b2[ch];
    }
  }
}

// ---------------------------------------------------------------- launch
extern "C" void kernel_launch(void* const* d_in, const int* in_sizes, int n_in,
                              void* d_out, int out_size, void* d_ws, size_t ws_size,
                              hipStream_t stream) {
  const float* pos  = (const float*)d_in[0];
  const float* feat = (const float*)d_in[1];
  const float* W1   = (const float*)d_in[2];
  const float* b1   = (const float*)d_in[3];
  const float* W2   = (const float*)d_in[4];
  const float* b2   = (const float*)d_in[5];
  float* out = (float*)d_out;
  char* ws = (char*)d_ws;
  // ws layout (aliases noted):
  //  [0,256K)              pos4 (prep..s2)        -> w1bf 64KB + w2bf 32KB (wprep..conv)
  //  [256K,917504)         knn u16 (s2..conv)
  //  [917504,13500416)     g1 [16384][16][24] u16 (s1x..s2) -> a_buf 4MB + c_buf 8MB (prec..conv)
  //  [13500416,14012416)   gcnt8 [16384][16][2] u8 (s1x..s2)
  //  [14012416,14077952)   tau [16384] f32 (s0..s1x)
  float4* pos4  = (float4*)ws;
  u16*    w1bf  = (u16*)ws;
  u16*    w2bf  = (u16*)(ws + 65536);
  u16*    knn   = (u16*)(ws + 262144);
  u16*    g1    = (u16*)(ws + 917504);
  u16*    a_buf = (u16*)(ws + 917504);
  float*  c_buf = (float*)(ws + 5111808);
  u8*     gcnt8 = (u8*)(ws + 13500416);
  float*  tau   = (float*)(ws + 14012416);
  if (ws_size < 14155776) return;   // insufficient scratch (would corrupt)

  knnconv_prep<<<64, 256, 0, stream>>>(pos, pos4);
  knnconv_s0<<<256, 1024, 0, stream>>>(pos4, tau);
  knnconv_s1x<<<2048, 256, 0, stream>>>(pos4, tau, g1, gcnt8);
  knnconv_s2<<<1024, 256, 0, stream>>>(pos4, g1, gcnt8, knn);
  knnconv_wprep<<<192, 256, 0, stream>>>(W1, W2, w1bf, w2bf);          // overwrites pos4 (dead)
  knnconv_prec<<<256, 256, 0, stream>>>(feat, w1bf, b1, a_buf, c_buf); // overwrites g1 (dead)
  knnconv_conv<<<2048, 256, 0, stream>>>(knn, a_buf, c_buf, w2bf, b2, out);
}